// Round 4
// baseline (316.920 us; speedup 1.0000x reference)
//
#include <hip/hip_runtime.h>

// DIM=256 H=8 HD=32 W=64 N=8192 nw=128
// xyz: T=40, off=20, hi=39 ; rgb: T=32, off=16, hi=31
// table element ((c*T+t)*8+h)*32+d == r*256 + h*32 + d, r=c*T+t

typedef __attribute__((ext_vector_type(8))) short short8;
typedef __attribute__((ext_vector_type(4))) float f32x4;

__device__ __forceinline__ unsigned short f2bf(float f) {
    union { float f; unsigned int u; } v; v.f = f;
    unsigned int r = v.u + 0x7FFFu + ((v.u >> 16) & 1u);
    return (unsigned short)(r >> 16);
}

// Wave-local ordering fence: drains this wave's outstanding DS ops (so
// atomic->read / read->write / write->atomic on wave-private LDS rows are
// ordered) without a cross-wave barrier. "memory" clobber stops compiler
// reordering of LDS accesses across it.
#define LFENCE() asm volatile("s_waitcnt lgkmcnt(0)" ::: "memory")

// ---------------------------------------------------------------------------
// QKV GEMM (bf16 MFMA), fp32 inputs cast inline during staging. (unchanged)
// ---------------------------------------------------------------------------
__global__ __launch_bounds__(256) void k_qkv(
    const float* __restrict__ A, const float* __restrict__ B,
    const float* __restrict__ bias,
    ushort* __restrict__ qb, ushort* __restrict__ kb, ushort* __restrict__ vb)
{
    __shared__ __align__(16) ushort a_s[128 * 72];
    __shared__ __align__(16) ushort b_s[64 * 72];
    const int tid = threadIdx.x;
    const int m0 = blockIdx.y * 128;
    const int n0 = blockIdx.x * 64;
    const int w = tid >> 6, wm = w >> 1, wn = w & 1;
    const int l4 = tid & 15, quad = (tid >> 4) & 3;
    f32x4 acc[4][2];
#pragma unroll
    for (int mt = 0; mt < 4; ++mt)
#pragma unroll
        for (int nt = 0; nt < 2; ++nt) acc[mt][nt] = (f32x4){0.f, 0.f, 0.f, 0.f};

    for (int k0 = 0; k0 < 256; k0 += 64) {
#pragma unroll
        for (int l = 0; l < 4; ++l) {
            int e = tid + l * 256;
            int row = e >> 3, kq = e & 7;
            const float* ap = A + (size_t)(m0 + row) * 256 + k0 + kq * 8;
            float4 v0 = *(const float4*)ap, v1 = *(const float4*)(ap + 4);
            union { ushort u[8]; uint4 v; } pk;
            pk.u[0] = f2bf(v0.x); pk.u[1] = f2bf(v0.y); pk.u[2] = f2bf(v0.z); pk.u[3] = f2bf(v0.w);
            pk.u[4] = f2bf(v1.x); pk.u[5] = f2bf(v1.y); pk.u[6] = f2bf(v1.z); pk.u[7] = f2bf(v1.w);
            *(uint4*)&a_s[row * 72 + kq * 8] = pk.v;
        }
#pragma unroll
        for (int l = 0; l < 2; ++l) {
            int e = tid + l * 256;
            int row = e >> 3, kq = e & 7;
            const float* bp = B + (size_t)(n0 + row) * 256 + k0 + kq * 8;
            float4 v0 = *(const float4*)bp, v1 = *(const float4*)(bp + 4);
            union { ushort u[8]; uint4 v; } pk;
            pk.u[0] = f2bf(v0.x); pk.u[1] = f2bf(v0.y); pk.u[2] = f2bf(v0.z); pk.u[3] = f2bf(v0.w);
            pk.u[4] = f2bf(v1.x); pk.u[5] = f2bf(v1.y); pk.u[6] = f2bf(v1.z); pk.u[7] = f2bf(v1.w);
            *(uint4*)&b_s[row * 72 + kq * 8] = pk.v;
        }
        __syncthreads();
#pragma unroll
        for (int kh = 0; kh < 2; ++kh) {
            short8 bf0 = *(const short8*)&b_s[(wn * 32 + l4) * 72 + kh * 32 + quad * 8];
            short8 bf1 = *(const short8*)&b_s[(wn * 32 + 16 + l4) * 72 + kh * 32 + quad * 8];
#pragma unroll
            for (int mt = 0; mt < 4; ++mt) {
                short8 af = *(const short8*)&a_s[(wm * 64 + mt * 16 + l4) * 72 + kh * 32 + quad * 8];
                acc[mt][0] = __builtin_amdgcn_mfma_f32_16x16x32_bf16(af, bf0, acc[mt][0], 0, 0, 0);
                acc[mt][1] = __builtin_amdgcn_mfma_f32_16x16x32_bf16(af, bf1, acc[mt][1], 0, 0, 0);
            }
        }
        __syncthreads();
    }
#pragma unroll
    for (int nt = 0; nt < 2; ++nt) {
        int c = n0 + wn * 32 + nt * 16 + l4;
        float bv = bias[c];
        int s = c >> 8, rem = c & 255, h = rem >> 5, d = rem & 31;
        ushort* dst = (s == 0) ? qb : ((s == 1) ? kb : vb);
        float mul = (s == 0) ? 0.17677669529663687f : 1.0f;
#pragma unroll
        for (int mt = 0; mt < 4; ++mt) {
            int mbase = m0 + wm * 64 + mt * 16 + quad * 4;
#pragma unroll
            for (int reg = 0; reg < 4; ++reg) {
                int m = mbase + reg;
                int nw = m >> 6, ii = m & 63;
                dst[((size_t)((nw * 8 + h) * 64 + ii)) * 32 + d] = f2bf((acc[mt][nt][reg] + bv) * mul);
            }
        }
    }
}

// ---------------------------------------------------------------------------
// MFMA attention per (window, head).  Round-12: 3-blocks/CU via reg cap 170.
//
// Occupancy ladder evidence:
//   r0:  LDS 55,296 (2 blk) + natural regs      -> 20.7%, 166 us
//   r1:  LDS 34,816 + cap 128 total             -> 38.7% BUT 185 MB spill, 202 us
//   r3:  LDS 34,816 + cap 256 total (lb 256,2)  -> 21.5%, 170 us  <- reg-limited!
// r3 reading: VGPR_Count=128 is ARCH only; unified total (arch+AGPR for MFMA
// accs) lands in (170,256] -> 2 waves/SIMD -> 2 blocks/CU. LDS no longer the
// limiter. The ladder is discrete: total<=170 -> 3 blocks/CU; <=128 -> 4
// (proven pathological, r1). 170 is ~10-20 regs below natural: expect mild
// rematerialization, not r1's 50% amputation.
// lb(256,3): cap = 512/3 = 170 total. Predict occ ~30-37%, dur ~110-130 us.
// Spill tripwire: WRITE_SIZE >> 10 MB -> revert to (256,2) and pivot to
// kernel-split (bias pass | softmax/AV pass) instead of residency.
// LDS: dbuf 10,496 + U 22,528 + cwf 1,536 = 34,560 B.
//
// Barrier discipline: dq-side gathers (useJ=false), all scatters, value-bias
// A-reads and bin zeroing touch ONLY wave-private dbuf rows (i/read-row in
// [w*16, w*16+16)) -> no __syncthreads, just LFENCE (own-wave DS drain).
// dk-side gathers (useJ=true) read all 64 j-rows -> real barriers.
// ---------------------------------------------------------------------------
#define DBS 41

__global__ __launch_bounds__(256, 3) void k_attn(
    const ushort* __restrict__ qb, const ushort* __restrict__ kb, const ushort* __restrict__ vb,
    const float* __restrict__ nco,
    const float* __restrict__ qxt, const float* __restrict__ kxt, const float* __restrict__ vxt,
    const float* __restrict__ qrt, const float* __restrict__ krt, const float* __restrict__ vrt,
    ushort* __restrict__ aout)
{
    __shared__ __align__(16) float dbuf[64 * DBS];   // 10,496 B: one c-slice of tgemm-out / bins
    __shared__ __align__(16) ushort U[11264];        // 22,528 B overlay region
    __shared__ __align__(16) float cwf[64 * 6];      // dedicated, alive all kernel
    // Phase A overlays:
    ushort* q_s  = U;              // [64][40]
    ushort* k_s  = U + 2560;       // [64][40]
    ushort* tbl  = U + 5120;       // [128][40]
    // Phase B overlays:
    ushort* attn_s = U;            // [64][72]
    ushort* v_t    = U + 4608;     // [32][72]
    ushort* vtbl   = U + 6912;     // [32][136]

    const int tid = threadIdx.x;
    const int n = blockIdx.x >> 3;
    const int h = blockIdx.x & 7;
    const int w = tid >> 6;
    const int lane = tid & 63;
    const int l4 = tid & 15;
    const int quad = (tid >> 4) & 3;

    const size_t base = (size_t)((n * 8 + h) * 64) * 32;

    // ---- stage q, k, coords ----
    {
        int row = tid >> 2, part = tid & 3;
        *(uint4*)&q_s[row * 40 + part * 8] = *(const uint4*)(qb + base + tid * 8);
        *(uint4*)&k_s[row * 40 + part * 8] = *(const uint4*)(kb + base + tid * 8);
    }
    if (tid < 64) {
        const float* cp = nco + (size_t)(n * 64 + tid) * 6;
        cwf[tid * 6 + 0] = cp[0] * 4.f; cwf[tid * 6 + 1] = cp[1] * 4.f;
        cwf[tid * 6 + 2] = cp[2] * 4.f; cwf[tid * 6 + 3] = cp[3] * 8.f;
        cwf[tid * 6 + 4] = cp[4] * 8.f; cwf[tid * 6 + 5] = cp[5] * 8.f;
    }

    auto stageTbl = [&](const float* tbg, int R, int Rpad) {
        for (int e = tid; e < R * 4; e += 256) {
            int r = e >> 2, part = e & 3;
            const float* src = tbg + (size_t)r * 256 + part * 8;
            float4 f0 = *(const float4*)src, f1 = *(const float4*)(src + 4);
            union { ushort u[8]; uint4 v; } pk;
            pk.u[0] = f2bf(f0.x); pk.u[1] = f2bf(f0.y); pk.u[2] = f2bf(f0.z); pk.u[3] = f2bf(f0.w);
            pk.u[4] = f2bf(f1.x); pk.u[5] = f2bf(f1.y); pk.u[6] = f2bf(f1.z); pk.u[7] = f2bf(f1.w);
            *(uint4*)&tbl[r * 40 + part * 8] = pk.v;
        }
        for (int e = tid; e < (Rpad - R) * 40; e += 256) tbl[R * 40 + e] = 0;
    };
    // No zero-pad needed: per-c value-bias reads only cols < c*T+T <= 120.
    auto stageVtbl = [&](const float* tbg, int R) {
        for (int e = tid; e < R * 4; e += 256) {
            int r = e >> 2, part = e & 3;
            const float* src = tbg + (size_t)r * 256 + part * 8;
            float4 f0 = *(const float4*)src, f1 = *(const float4*)(src + 4);
            int d0 = part * 8;
            vtbl[(d0 + 0) * 136 + r] = f2bf(f0.x);
            vtbl[(d0 + 1) * 136 + r] = f2bf(f0.y);
            vtbl[(d0 + 2) * 136 + r] = f2bf(f0.z);
            vtbl[(d0 + 3) * 136 + r] = f2bf(f0.w);
            vtbl[(d0 + 4) * 136 + r] = f2bf(f1.x);
            vtbl[(d0 + 5) * 136 + r] = f2bf(f1.y);
            vtbl[(d0 + 6) * 136 + r] = f2bf(f1.z);
            vtbl[(d0 + 7) * 136 + r] = f2bf(f1.w);
        }
    };
    auto stageVt = [&]() {
        int j = tid >> 2, d0 = (tid & 3) * 8;
        uint4 pk = *(const uint4*)(vb + base + tid * 8);
        const ushort* u = (const ushort*)&pk;
#pragma unroll
        for (int ii = 0; ii < 8; ++ii) v_t[(d0 + ii) * 72 + j] = u[ii];
    };

    float lg[4][4];   // [tt][reg]: row i = w*16+quad*4+reg, col j = tt*16+l4

    // table-GEMM for component c: contracts a_s rows with tbl rows
    // [c*T, c*T+T), writing the T local bins into dbuf cols [0, T).
    auto tgemmC = [&](const ushort* a_s, int c, int T) {
        short8 af = *(const short8*)&a_s[(w * 16 + l4) * 40 + quad * 8];
        const int NT = (T == 40) ? 3 : 2;
        for (int tt = 0; tt < NT; ++tt) {
            short8 bf = *(const short8*)&tbl[(c * T + tt * 16 + l4) * 40 + quad * 8];
            f32x4 a = {0.f, 0.f, 0.f, 0.f};
            a = __builtin_amdgcn_mfma_f32_16x16x32_bf16(af, bf, a, 0, 0, 0);
            int col = tt * 16 + l4;
            int rb = w * 16 + quad * 4;
            if (col < T) {
                dbuf[(rb + 0) * DBS + col] = a[0];
                dbuf[(rb + 1) * DBS + col] = a[1];
                dbuf[(rb + 2) * DBS + col] = a[2];
                dbuf[(rb + 3) * DBS + col] = a[3];
            }
        }
    };
    // Indices recomputed from cwf at every use site (no idx register arrays).
    auto gatherC = [&](int cc, int off, int hi, bool useJ) {
#pragma unroll
        for (int tt = 0; tt < 4; ++tt) {
            int j = tt * 16 + l4;
            float cj = cwf[j * 6 + cc];
#pragma unroll
            for (int reg = 0; reg < 4; ++reg) {
                int i = w * 16 + quad * 4 + reg;
                int x = min(max((int)floorf(cwf[i * 6 + cc] - cj) + off, 0), hi);
                lg[tt][reg] += dbuf[(useJ ? j : i) * DBS + x];
            }
        }
    };
    auto scatterC = [&](int cc, int off, int hi) {
#pragma unroll
        for (int tt = 0; tt < 4; ++tt) {
            int j = tt * 16 + l4;
            float cj = cwf[j * 6 + cc];
#pragma unroll
            for (int reg = 0; reg < 4; ++reg) {
                int i = w * 16 + quad * 4 + reg;
                int x = min(max((int)floorf(cwf[i * 6 + cc] - cj) + off, 0), hi);
                atomicAdd(&dbuf[i * DBS + x], lg[tt][reg]);
            }
        }
    };
    // zero this wave's 16 bin rows only (wave-private)
    auto zeroOwn = [&]() {
        float* rb = &dbuf[w * 16 * DBS];
        for (int e = lane; e < 16 * DBS; e += 64) rb[e] = 0.f;
    };

    stageTbl(kxt + h * 32, 120, 128);
    __syncthreads();

    // ---- QK logits ----
    {
        short8 aq = *(const short8*)&q_s[(w * 16 + l4) * 40 + quad * 8];
#pragma unroll
        for (int tt = 0; tt < 4; ++tt) {
            short8 bk = *(const short8*)&k_s[(tt * 16 + l4) * 40 + quad * 8];
            f32x4 r = {0.f, 0.f, 0.f, 0.f};
            r = __builtin_amdgcn_mfma_f32_16x16x32_bf16(aq, bk, r, 0, 0, 0);
            lg[tt][0] = r[0]; lg[tt][1] = r[1]; lg[tt][2] = r[2]; lg[tt][3] = r[3];
        }
    }

    // ---- dk (bias_k): cross-wave j-row gathers -> real barriers ----
    tgemmC(k_s, 0, 40);
    __syncthreads();
    gatherC(0, 20, 39, true);
    __syncthreads();
    tgemmC(k_s, 1, 40);
    __syncthreads();
    gatherC(1, 20, 39, true);
    __syncthreads();
    tgemmC(k_s, 2, 40);
    __syncthreads();
    gatherC(2, 20, 39, true);
    stageTbl(krt + h * 32, 96, 96);
    __syncthreads();
    tgemmC(k_s, 0, 32);
    __syncthreads();
    gatherC(3, 16, 31, true);
    __syncthreads();
    tgemmC(k_s, 1, 32);
    __syncthreads();
    gatherC(4, 16, 31, true);
    __syncthreads();
    tgemmC(k_s, 2, 32);
    __syncthreads();
    gatherC(5, 16, 31, true);
    stageTbl(qxt + h * 32, 120, 128);
    __syncthreads();

    // ---- dq (bias_q): wave-private i-rows -> fences only ----
    tgemmC(q_s, 0, 40); LFENCE();
    gatherC(0, 20, 39, false); LFENCE();
    tgemmC(q_s, 1, 40); LFENCE();
    gatherC(1, 20, 39, false); LFENCE();
    tgemmC(q_s, 2, 40);
    __syncthreads();                       // others must finish reading tbl
    gatherC(2, 20, 39, false);
    stageTbl(qrt + h * 32, 96, 96);
    __syncthreads();
    tgemmC(q_s, 0, 32); LFENCE();
    gatherC(3, 16, 31, false); LFENCE();
    tgemmC(q_s, 1, 32); LFENCE();
    gatherC(4, 16, 31, false); LFENCE();
    tgemmC(q_s, 2, 32);
    __syncthreads();                       // tbl/k_s regions go dead here
    gatherC(5, 16, 31, false);
    stageVtbl(vxt + h * 32, 120);
    stageVt();
    __syncthreads();

    // ---- softmax ----
#pragma unroll
    for (int reg = 0; reg < 4; ++reg) {
        float m = fmaxf(fmaxf(lg[0][reg], lg[1][reg]), fmaxf(lg[2][reg], lg[3][reg]));
        m = fmaxf(m, __shfl_xor(m, 1));
        m = fmaxf(m, __shfl_xor(m, 2));
        m = fmaxf(m, __shfl_xor(m, 4));
        m = fmaxf(m, __shfl_xor(m, 8));
        float s = 0.f;
#pragma unroll
        for (int tt = 0; tt < 4; ++tt) { lg[tt][reg] = __expf(lg[tt][reg] - m); s += lg[tt][reg]; }
        s += __shfl_xor(s, 1); s += __shfl_xor(s, 2);
        s += __shfl_xor(s, 4); s += __shfl_xor(s, 8);
        float inv = 1.f / s;
#pragma unroll
        for (int tt = 0; tt < 4; ++tt) lg[tt][reg] *= inv;
    }
#pragma unroll
    for (int tt = 0; tt < 4; ++tt)
#pragma unroll
        for (int reg = 0; reg < 4; ++reg)
            attn_s[(w * 16 + quad * 4 + reg) * 72 + tt * 16 + l4] = f2bf(lg[tt][reg]);
    zeroOwn();
    __syncthreads();

    // ---- AV ----
    f32x4 acc0 = {0.f, 0.f, 0.f, 0.f}, acc1 = {0.f, 0.f, 0.f, 0.f};
#pragma unroll
    for (int s = 0; s < 2; ++s) {
        short8 af = *(const short8*)&attn_s[(w * 16 + l4) * 72 + s * 32 + quad * 8];
        short8 b0 = *(const short8*)&v_t[l4 * 72 + s * 32 + quad * 8];
        short8 b1 = *(const short8*)&v_t[(16 + l4) * 72 + s * 32 + quad * 8];
        acc0 = __builtin_amdgcn_mfma_f32_16x16x32_bf16(af, b0, acc0, 0, 0, 0);
        acc1 = __builtin_amdgcn_mfma_f32_16x16x32_bf16(af, b1, acc1, 0, 0, 0);
    }

    // value-bias contraction for component c: bins cols [0,T) x vtbl cols
    // [c*T, c*T+T). A-frag rows are wave-private.
    auto atgemmC = [&](int c, int T, int S) {
#pragma unroll
        for (int s = 0; s < S; ++s) {
            int koff = s * 32 + quad * 8;
            short8 af = {0, 0, 0, 0, 0, 0, 0, 0};
            int kr = 0;
            if (koff < T) {
                const float* ap = &dbuf[(w * 16 + l4) * DBS + koff];
#pragma unroll
                for (int ii = 0; ii < 8; ++ii) af[ii] = (short)f2bf(ap[ii]);
                kr = c * T + koff;
            }
            short8 b0 = *(const short8*)&vtbl[l4 * 136 + kr];
            short8 b1 = *(const short8*)&vtbl[(16 + l4) * 136 + kr];
            acc0 = __builtin_amdgcn_mfma_f32_16x16x32_bf16(af, b0, acc0, 0, 0, 0);
            acc1 = __builtin_amdgcn_mfma_f32_16x16x32_bf16(af, b1, acc1, 0, 0, 0);
        }
    };

    // ---- value-bias xyz: all dbuf traffic wave-private -> fences only ----
    scatterC(0, 20, 39); LFENCE();
    atgemmC(0, 40, 2); LFENCE();
    zeroOwn(); LFENCE();
    scatterC(1, 20, 39); LFENCE();
    atgemmC(1, 40, 2); LFENCE();
    zeroOwn(); LFENCE();
    scatterC(2, 20, 39); LFENCE();
    atgemmC(2, 40, 2);
    __syncthreads();                       // all waves done reading vtbl(vxt)
    zeroOwn();
    stageVtbl(vrt + h * 32, 96);
    __syncthreads();

    // ---- value-bias rgb ----
    scatterC(3, 16, 31); LFENCE();
    atgemmC(0, 32, 1); LFENCE();
    zeroOwn(); LFENCE();
    scatterC(4, 16, 31); LFENCE();
    atgemmC(1, 32, 1); LFENCE();
    zeroOwn(); LFENCE();
    scatterC(5, 16, 31); LFENCE();
    atgemmC(2, 32, 1);

    // ---- epilogue: bf16 ao[i][h*32+d] ----
    {
        ushort* op = aout + (size_t)(n * 64 + w * 16 + quad * 4) * 256 + h * 32;
#pragma unroll
        for (int reg = 0; reg < 4; ++reg) {
            op[reg * 256 + l4] = f2bf(acc0[reg]);
            op[reg * 256 + 16 + l4] = f2bf(acc1[reg]);
        }
    }
}

// ---------------------------------------------------------------------------
// Proj GEMM (bf16 MFMA): out = ao(bf16) @ proj_w(fp32, cast inline)^T + pb
// ---------------------------------------------------------------------------
__global__ __launch_bounds__(256) void k_proj(
    const ushort* __restrict__ A, const float* __restrict__ B,
    const float* __restrict__ bias, float* __restrict__ out)
{
    __shared__ __align__(16) ushort a_s[128 * 72];
    __shared__ __align__(16) ushort b_s[64 * 72];
    const int tid = threadIdx.x;
    const int m0 = blockIdx.y * 128;
    const int n0 = blockIdx.x * 64;
    const int w = tid >> 6, wm = w >> 1, wn = w & 1;
    const int l4 = tid & 15, quad = (tid >> 4) & 3;
    f32x4 acc[4][2];
#pragma unroll
    for (int mt = 0; mt < 4; ++mt)
#pragma unroll
        for (int nt = 0; nt < 2; ++nt) acc[mt][nt] = (f32x4){0.f, 0.f, 0.f, 0.f};

    for (int k0 = 0; k0 < 256; k0 += 64) {
#pragma unroll
        for (int l = 0; l < 4; ++l) {
            int e = tid + l * 256;
            int row = e >> 3, kq = e & 7;
            *(uint4*)&a_s[row * 72 + kq * 8] =
                *(const uint4*)(A + (size_t)(m0 + row) * 256 + k0 + kq * 8);
        }
#pragma unroll
        for (int l = 0; l < 2; ++l) {
            int e = tid + l * 256;
            int row = e >> 3, kq = e & 7;
            const float* bp = B + (size_t)(n0 + row) * 256 + k0 + kq * 8;
            float4 v0 = *(const float4*)bp, v1 = *(const float4*)(bp + 4);
            union { ushort u[8]; uint4 v; } pk;
            pk.u[0] = f2bf(v0.x); pk.u[1] = f2bf(v0.y); pk.u[2] = f2bf(v0.z); pk.u[3] = f2bf(v0.w);
            pk.u[4] = f2bf(v1.x); pk.u[5] = f2bf(v1.y); pk.u[6] = f2bf(v1.z); pk.u[7] = f2bf(v1.w);
            *(uint4*)&b_s[row * 72 + kq * 8] = pk.v;
        }
        __syncthreads();
#pragma unroll
        for (int kh = 0; kh < 2; ++kh) {
            short8 bf0 = *(const short8*)&b_s[(wn * 32 + l4) * 72 + kh * 32 + quad * 8];
            short8 bf1 = *(const short8*)&b_s[(wn * 32 + 16 + l4) * 72 + kh * 32 + quad * 8];
#pragma unroll
            for (int mt = 0; mt < 4; ++mt) {
                short8 af = *(const short8*)&a_s[(wm * 64 + mt * 16 + l4) * 72 + kh * 32 + quad * 8];
                acc[mt][0] = __builtin_amdgcn_mfma_f32_16x16x32_bf16(af, bf0, acc[mt][0], 0, 0, 0);
                acc[mt][1] = __builtin_amdgcn_mfma_f32_16x16x32_bf16(af, bf1, acc[mt][1], 0, 0, 0);
            }
        }
        __syncthreads();
    }
#pragma unroll
    for (int nt = 0; nt < 2; ++nt) {
        int c = n0 + wn * 32 + nt * 16 + l4;
        float bv = bias[c];
#pragma unroll
        for (int mt = 0; mt < 4; ++mt) {
            int mbase = m0 + wm * 64 + mt * 16 + quad * 4;
#pragma unroll
            for (int reg = 0; reg < 4; ++reg)
                out[(size_t)(mbase + reg) * 256 + c] = acc[mt][nt][reg] + bv;
        }
    }
}

extern "C" void kernel_launch(void* const* d_in, const int* in_sizes, int n_in,
                              void* d_out, int out_size, void* d_ws, size_t ws_size,
                              hipStream_t stream)
{
    const float* feats = (const float*)d_in[0];
    const float* nco   = (const float*)d_in[1];
    const float* qkvw  = (const float*)d_in[2];
    const float* qkvb  = (const float*)d_in[3];
    const float* qxt   = (const float*)d_in[4];
    const float* kxt   = (const float*)d_in[5];
    const float* vxt   = (const float*)d_in[6];
    const float* qrt   = (const float*)d_in[7];
    const float* krt   = (const float*)d_in[8];
    const float* vrt   = (const float*)d_in[9];
    const float* pw    = (const float*)d_in[10];
    const float* pb    = (const float*)d_in[11];
    float* out = (float*)d_out;

    ushort* qb  = (ushort*)d_ws;                       // [128][8][64][32] bf16
    ushort* kb  = qb + (size_t)2097152;
    ushort* vb  = kb + (size_t)2097152;
    ushort* aob = vb + (size_t)2097152;                // [8192][256] bf16

    k_qkv<<<dim3(12, 64), 256, 0, stream>>>(feats, qkvw, qkvb, qb, kb, vb);
    k_attn<<<dim3(1024), 256, 0, stream>>>(qb, kb, vb, nco, qxt, kxt, vxt, qrt, krt, vrt, aob);
    k_proj<<<dim3(4, 64), 256, 0, stream>>>(aob, pw, pb, out);
}

// Round 5
// 274.500 us; speedup vs baseline: 1.1545x; 1.1545x over previous
//
#include <hip/hip_runtime.h>

// DIM=256 H=8 HD=32 W=64 N=8192 nw=128
// xyz: T=40, off=20, hi=39 ; rgb: T=32, off=16, hi=31
// table element ((c*T+t)*8+h)*32+d == r*256 + h*32 + d, r=c*T+t

typedef __attribute__((ext_vector_type(8))) short short8;
typedef __attribute__((ext_vector_type(4))) float f32x4;

__device__ __forceinline__ unsigned short f2bf(float f) {
    union { float f; unsigned int u; } v; v.f = f;
    unsigned int r = v.u + 0x7FFFu + ((v.u >> 16) & 1u);
    return (unsigned short)(r >> 16);
}

// Wave-local ordering fence: drains this wave's outstanding DS ops.
#define LFENCE() asm volatile("s_waitcnt lgkmcnt(0)" ::: "memory")

// ---------------------------------------------------------------------------
// QKV GEMM (bf16 MFMA), fp32 inputs cast inline during staging. (unchanged)
// ---------------------------------------------------------------------------
__global__ __launch_bounds__(256) void k_qkv(
    const float* __restrict__ A, const float* __restrict__ B,
    const float* __restrict__ bias,
    ushort* __restrict__ qb, ushort* __restrict__ kb, ushort* __restrict__ vb)
{
    __shared__ __align__(16) ushort a_s[128 * 72];
    __shared__ __align__(16) ushort b_s[64 * 72];
    const int tid = threadIdx.x;
    const int m0 = blockIdx.y * 128;
    const int n0 = blockIdx.x * 64;
    const int w = tid >> 6, wm = w >> 1, wn = w & 1;
    const int l4 = tid & 15, quad = (tid >> 4) & 3;
    f32x4 acc[4][2];
#pragma unroll
    for (int mt = 0; mt < 4; ++mt)
#pragma unroll
        for (int nt = 0; nt < 2; ++nt) acc[mt][nt] = (f32x4){0.f, 0.f, 0.f, 0.f};

    for (int k0 = 0; k0 < 256; k0 += 64) {
#pragma unroll
        for (int l = 0; l < 4; ++l) {
            int e = tid + l * 256;
            int row = e >> 3, kq = e & 7;
            const float* ap = A + (size_t)(m0 + row) * 256 + k0 + kq * 8;
            float4 v0 = *(const float4*)ap, v1 = *(const float4*)(ap + 4);
            union { ushort u[8]; uint4 v; } pk;
            pk.u[0] = f2bf(v0.x); pk.u[1] = f2bf(v0.y); pk.u[2] = f2bf(v0.z); pk.u[3] = f2bf(v0.w);
            pk.u[4] = f2bf(v1.x); pk.u[5] = f2bf(v1.y); pk.u[6] = f2bf(v1.z); pk.u[7] = f2bf(v1.w);
            *(uint4*)&a_s[row * 72 + kq * 8] = pk.v;
        }
#pragma unroll
        for (int l = 0; l < 2; ++l) {
            int e = tid + l * 256;
            int row = e >> 3, kq = e & 7;
            const float* bp = B + (size_t)(n0 + row) * 256 + k0 + kq * 8;
            float4 v0 = *(const float4*)bp, v1 = *(const float4*)(bp + 4);
            union { ushort u[8]; uint4 v; } pk;
            pk.u[0] = f2bf(v0.x); pk.u[1] = f2bf(v0.y); pk.u[2] = f2bf(v0.z); pk.u[3] = f2bf(v0.w);
            pk.u[4] = f2bf(v1.x); pk.u[5] = f2bf(v1.y); pk.u[6] = f2bf(v1.z); pk.u[7] = f2bf(v1.w);
            *(uint4*)&b_s[row * 72 + kq * 8] = pk.v;
        }
        __syncthreads();
#pragma unroll
        for (int kh = 0; kh < 2; ++kh) {
            short8 bf0 = *(const short8*)&b_s[(wn * 32 + l4) * 72 + kh * 32 + quad * 8];
            short8 bf1 = *(const short8*)&b_s[(wn * 32 + 16 + l4) * 72 + kh * 32 + quad * 8];
#pragma unroll
            for (int mt = 0; mt < 4; ++mt) {
                short8 af = *(const short8*)&a_s[(wm * 64 + mt * 16 + l4) * 72 + kh * 32 + quad * 8];
                acc[mt][0] = __builtin_amdgcn_mfma_f32_16x16x32_bf16(af, bf0, acc[mt][0], 0, 0, 0);
                acc[mt][1] = __builtin_amdgcn_mfma_f32_16x16x32_bf16(af, bf1, acc[mt][1], 0, 0, 0);
            }
        }
        __syncthreads();
    }
#pragma unroll
    for (int nt = 0; nt < 2; ++nt) {
        int c = n0 + wn * 32 + nt * 16 + l4;
        float bv = bias[c];
        int s = c >> 8, rem = c & 255, h = rem >> 5, d = rem & 31;
        ushort* dst = (s == 0) ? qb : ((s == 1) ? kb : vb);
        float mul = (s == 0) ? 0.17677669529663687f : 1.0f;
#pragma unroll
        for (int mt = 0; mt < 4; ++mt) {
            int mbase = m0 + wm * 64 + mt * 16 + quad * 4;
#pragma unroll
            for (int reg = 0; reg < 4; ++reg) {
                int m = mbase + reg;
                int nw = m >> 6, ii = m & 63;
                dst[((size_t)((nw * 8 + h) * 64 + ii)) * 32 + d] = f2bf((acc[mt][nt][reg] + bv) * mul);
            }
        }
    }
}

// ---------------------------------------------------------------------------
// Round-13: attention split in two.  Register-ladder post-mortems (r1/r3/r4):
// monolith natural pressure ~190-200 total (arch+acc, unified file) -> locked
// at 2 blocks/CU; any launch-bounds cap below that splits the file 50/50 and
// spills (r1: 117MB, r4: 78MB scratch traffic). So: SPLIT at the bias_k |
// bias_q boundary to cut live state per kernel.
//
// k_bias computes logitsT = K.Q^T + bias_k with TRANSPOSED output (rows=j):
// bias_k[i,j] needs dk[j, bin(i,j)] -> j = own MFMA output row -> all six
// dk gathers are wave-private (LFENCE only; 13 barriers -> 3). No AV accs,
// no V staging. Writes logitsT f32 to workspace (16.7 MB, ~3 us HBM).
// Gather sign: bin = floor(cw[col i] - cw[own row j]) + off  (ref: cw_i-cw_j).
//
// k_av loads logitsT (transposed read, L2-served, each elem read once), adds
// bias_q (own-row gathers), softmax, AV, value-bias — r3's back half with
// k_s/QK/dk live-ranges gone.
//
// Both: __launch_bounds__(256,2) = generous cap, occupancy emerges from
// natural usage (floor(512/total) waves/SIMD).
// Spill tripwire: VGPR_Count ~ cap/2 (64/84 pattern) + WRITE_SIZE beyond the
// intended 16.4 MB (k_bias) / 4 MB (k_av).
// ---------------------------------------------------------------------------
#define DBS 41

__global__ __launch_bounds__(256, 2) void k_bias(
    const ushort* __restrict__ qb, const ushort* __restrict__ kb,
    const float* __restrict__ nco,
    const float* __restrict__ kxt, const float* __restrict__ krt,
    float* __restrict__ lgt)
{
    __shared__ __align__(16) float dbuf[64 * DBS];    // 10,496 B
    __shared__ __align__(16) ushort q_s[64 * 40];     //  5,120 B
    __shared__ __align__(16) ushort k_s[64 * 40];     //  5,120 B
    __shared__ __align__(16) ushort tbl[128 * 40];    // 10,240 B
    __shared__ __align__(16) float cwf[64 * 6];       //  1,536 B  (32.5 KB total)

    const int tid = threadIdx.x;
    const int n = blockIdx.x >> 3;
    const int h = blockIdx.x & 7;
    const int w = tid >> 6;
    const int l4 = tid & 15;
    const int quad = (tid >> 4) & 3;

    const size_t base = (size_t)((n * 8 + h) * 64) * 32;

    {
        int row = tid >> 2, part = tid & 3;
        *(uint4*)&q_s[row * 40 + part * 8] = *(const uint4*)(qb + base + tid * 8);
        *(uint4*)&k_s[row * 40 + part * 8] = *(const uint4*)(kb + base + tid * 8);
    }
    if (tid < 64) {
        const float* cp = nco + (size_t)(n * 64 + tid) * 6;
        cwf[tid * 6 + 0] = cp[0] * 4.f; cwf[tid * 6 + 1] = cp[1] * 4.f;
        cwf[tid * 6 + 2] = cp[2] * 4.f; cwf[tid * 6 + 3] = cp[3] * 8.f;
        cwf[tid * 6 + 4] = cp[4] * 8.f; cwf[tid * 6 + 5] = cp[5] * 8.f;
    }

    auto stageTbl = [&](const float* tbg, int R, int Rpad) {
        for (int e = tid; e < R * 4; e += 256) {
            int r = e >> 2, part = e & 3;
            const float* src = tbg + (size_t)r * 256 + part * 8;
            float4 f0 = *(const float4*)src, f1 = *(const float4*)(src + 4);
            union { ushort u[8]; uint4 v; } pk;
            pk.u[0] = f2bf(f0.x); pk.u[1] = f2bf(f0.y); pk.u[2] = f2bf(f0.z); pk.u[3] = f2bf(f0.w);
            pk.u[4] = f2bf(f1.x); pk.u[5] = f2bf(f1.y); pk.u[6] = f2bf(f1.z); pk.u[7] = f2bf(f1.w);
            *(uint4*)&tbl[r * 40 + part * 8] = pk.v;
        }
        for (int e = tid; e < (Rpad - R) * 40; e += 256) tbl[R * 40 + e] = 0;
    };

    float lg[4][4];   // [tt][reg]: TRANSPOSED — row j = w*16+quad*4+reg, col i = tt*16+l4

    auto tgemmC = [&](const ushort* a_s, int c, int T) {
        short8 af = *(const short8*)&a_s[(w * 16 + l4) * 40 + quad * 8];
        const int NT = (T == 40) ? 3 : 2;
        for (int tt = 0; tt < NT; ++tt) {
            short8 bf = *(const short8*)&tbl[(c * T + tt * 16 + l4) * 40 + quad * 8];
            f32x4 a = {0.f, 0.f, 0.f, 0.f};
            a = __builtin_amdgcn_mfma_f32_16x16x32_bf16(af, bf, a, 0, 0, 0);
            int col = tt * 16 + l4;
            int rb = w * 16 + quad * 4;
            if (col < T) {
                dbuf[(rb + 0) * DBS + col] = a[0];
                dbuf[(rb + 1) * DBS + col] = a[1];
                dbuf[(rb + 2) * DBS + col] = a[2];
                dbuf[(rb + 3) * DBS + col] = a[3];
            }
        }
    };
    // transposed gather: own row j, col i; bin = floor(cw_i - cw_j) + off
    auto gatherT = [&](int cc, int off, int hi) {
#pragma unroll
        for (int tt = 0; tt < 4; ++tt) {
            int i = tt * 16 + l4;
            float ci = cwf[i * 6 + cc];
#pragma unroll
            for (int reg = 0; reg < 4; ++reg) {
                int j = w * 16 + quad * 4 + reg;
                int x = min(max((int)floorf(ci - cwf[j * 6 + cc]) + off, 0), hi);
                lg[tt][reg] += dbuf[j * DBS + x];
            }
        }
    };

    stageTbl(kxt + h * 32, 120, 128);
    __syncthreads();

    // ---- logitsT = K.Q^T (output rows = k-row j, wave-private) ----
    {
        short8 ak = *(const short8*)&k_s[(w * 16 + l4) * 40 + quad * 8];
#pragma unroll
        for (int tt = 0; tt < 4; ++tt) {
            short8 bq = *(const short8*)&q_s[(tt * 16 + l4) * 40 + quad * 8];
            f32x4 r = {0.f, 0.f, 0.f, 0.f};
            r = __builtin_amdgcn_mfma_f32_16x16x32_bf16(ak, bq, r, 0, 0, 0);
            lg[tt][0] = r[0]; lg[tt][1] = r[1]; lg[tt][2] = r[2]; lg[tt][3] = r[3];
        }
    }

    // ---- bias_k xyz: all wave-private ----
    tgemmC(k_s, 0, 40); LFENCE();
    gatherT(0, 20, 39); LFENCE();
    tgemmC(k_s, 1, 40); LFENCE();
    gatherT(1, 20, 39); LFENCE();
    tgemmC(k_s, 2, 40); LFENCE();
    gatherT(2, 20, 39);
    __syncthreads();                       // all waves done reading tbl(kxt)
    stageTbl(krt + h * 32, 96, 96);
    __syncthreads();
    // ---- bias_k rgb ----
    tgemmC(k_s, 0, 32); LFENCE();
    gatherT(3, 16, 31); LFENCE();
    tgemmC(k_s, 1, 32); LFENCE();
    gatherT(4, 16, 31); LFENCE();
    tgemmC(k_s, 2, 32); LFENCE();
    gatherT(5, 16, 31);

    // ---- store logitsT f32: lgt[nh][j][i] ----
    {
        float* lp = lgt + (size_t)(n * 8 + h) * 4096;
#pragma unroll
        for (int tt = 0; tt < 4; ++tt)
#pragma unroll
            for (int reg = 0; reg < 4; ++reg)
                lp[(w * 16 + quad * 4 + reg) * 64 + tt * 16 + l4] = lg[tt][reg];
    }
}

__global__ __launch_bounds__(256, 2) void k_av(
    const ushort* __restrict__ qb, const ushort* __restrict__ vb,
    const float* __restrict__ nco,
    const float* __restrict__ qxt, const float* __restrict__ vxt,
    const float* __restrict__ qrt, const float* __restrict__ vrt,
    const float* __restrict__ lgt,
    ushort* __restrict__ aout)
{
    __shared__ __align__(16) float dbuf[64 * DBS];   // 10,496 B
    __shared__ __align__(16) ushort U[11264];        // 22,528 B overlay region
    __shared__ __align__(16) float cwf[64 * 6];      //  1,536 B (34.5 KB total)
    // Phase A overlays:
    ushort* q_s  = U;              // [64][40] = 2560 ushorts
    ushort* tbl  = U + 2560;       // [128][40] = 5120 ushorts, ends 7680
    // Phase B overlays:
    ushort* attn_s = U;            // [64][72] = 4608 ushorts
    ushort* v_t    = U + 4608;     // [32][72] = 2304, ends 6912
    ushort* vtbl   = U + 6912;     // [32][136] = 4352, ends 11264

    const int tid = threadIdx.x;
    const int n = blockIdx.x >> 3;
    const int h = blockIdx.x & 7;
    const int w = tid >> 6;
    const int lane = tid & 63;
    const int l4 = tid & 15;
    const int quad = (tid >> 4) & 3;

    const size_t base = (size_t)((n * 8 + h) * 64) * 32;

    {
        int row = tid >> 2, part = tid & 3;
        *(uint4*)&q_s[row * 40 + part * 8] = *(const uint4*)(qb + base + tid * 8);
    }
    if (tid < 64) {
        const float* cp = nco + (size_t)(n * 64 + tid) * 6;
        cwf[tid * 6 + 0] = cp[0] * 4.f; cwf[tid * 6 + 1] = cp[1] * 4.f;
        cwf[tid * 6 + 2] = cp[2] * 4.f; cwf[tid * 6 + 3] = cp[3] * 8.f;
        cwf[tid * 6 + 4] = cp[4] * 8.f; cwf[tid * 6 + 5] = cp[5] * 8.f;
    }

    auto stageTbl = [&](const float* tbg, int R, int Rpad) {
        for (int e = tid; e < R * 4; e += 256) {
            int r = e >> 2, part = e & 3;
            const float* src = tbg + (size_t)r * 256 + part * 8;
            float4 f0 = *(const float4*)src, f1 = *(const float4*)(src + 4);
            union { ushort u[8]; uint4 v; } pk;
            pk.u[0] = f2bf(f0.x); pk.u[1] = f2bf(f0.y); pk.u[2] = f2bf(f0.z); pk.u[3] = f2bf(f0.w);
            pk.u[4] = f2bf(f1.x); pk.u[5] = f2bf(f1.y); pk.u[6] = f2bf(f1.z); pk.u[7] = f2bf(f1.w);
            *(uint4*)&tbl[r * 40 + part * 8] = pk.v;
        }
        for (int e = tid; e < (Rpad - R) * 40; e += 256) tbl[R * 40 + e] = 0;
    };
    auto stageVtbl = [&](const float* tbg, int R) {
        for (int e = tid; e < R * 4; e += 256) {
            int r = e >> 2, part = e & 3;
            const float* src = tbg + (size_t)r * 256 + part * 8;
            float4 f0 = *(const float4*)src, f1 = *(const float4*)(src + 4);
            int d0 = part * 8;
            vtbl[(d0 + 0) * 136 + r] = f2bf(f0.x);
            vtbl[(d0 + 1) * 136 + r] = f2bf(f0.y);
            vtbl[(d0 + 2) * 136 + r] = f2bf(f0.z);
            vtbl[(d0 + 3) * 136 + r] = f2bf(f0.w);
            vtbl[(d0 + 4) * 136 + r] = f2bf(f1.x);
            vtbl[(d0 + 5) * 136 + r] = f2bf(f1.y);
            vtbl[(d0 + 6) * 136 + r] = f2bf(f1.z);
            vtbl[(d0 + 7) * 136 + r] = f2bf(f1.w);
        }
    };
    auto stageVt = [&]() {
        int j = tid >> 2, d0 = (tid & 3) * 8;
        uint4 pk = *(const uint4*)(vb + base + tid * 8);
        const ushort* u = (const ushort*)&pk;
#pragma unroll
        for (int ii = 0; ii < 8; ++ii) v_t[(d0 + ii) * 72 + j] = u[ii];
    };

    // ---- load logitsT transposed into normal layout lg[i own-row][j col] ----
    float lg[4][4];
    {
        const float* lp = lgt + (size_t)(n * 8 + h) * 4096;
        int i = w * 16 + quad * 4;
#pragma unroll
        for (int tt = 0; tt < 4; ++tt)
#pragma unroll
            for (int reg = 0; reg < 4; ++reg)
                lg[tt][reg] = lp[(size_t)(tt * 16 + l4) * 64 + i + reg];
    }

    auto tgemmC = [&](const ushort* a_s, int c, int T) {
        short8 af = *(const short8*)&a_s[(w * 16 + l4) * 40 + quad * 8];
        const int NT = (T == 40) ? 3 : 2;
        for (int tt = 0; tt < NT; ++tt) {
            short8 bf = *(const short8*)&tbl[(c * T + tt * 16 + l4) * 40 + quad * 8];
            f32x4 a = {0.f, 0.f, 0.f, 0.f};
            a = __builtin_amdgcn_mfma_f32_16x16x32_bf16(af, bf, a, 0, 0, 0);
            int col = tt * 16 + l4;
            int rb = w * 16 + quad * 4;
            if (col < T) {
                dbuf[(rb + 0) * DBS + col] = a[0];
                dbuf[(rb + 1) * DBS + col] = a[1];
                dbuf[(rb + 2) * DBS + col] = a[2];
                dbuf[(rb + 3) * DBS + col] = a[3];
            }
        }
    };
    // own-row gather: bin = floor(cw_i(own) - cw_j(col)) + off
    auto gatherC = [&](int cc, int off, int hi) {
#pragma unroll
        for (int tt = 0; tt < 4; ++tt) {
            int j = tt * 16 + l4;
            float cj = cwf[j * 6 + cc];
#pragma unroll
            for (int reg = 0; reg < 4; ++reg) {
                int i = w * 16 + quad * 4 + reg;
                int x = min(max((int)floorf(cwf[i * 6 + cc] - cj) + off, 0), hi);
                lg[tt][reg] += dbuf[i * DBS + x];
            }
        }
    };
    auto scatterC = [&](int cc, int off, int hi) {
#pragma unroll
        for (int tt = 0; tt < 4; ++tt) {
            int j = tt * 16 + l4;
            float cj = cwf[j * 6 + cc];
#pragma unroll
            for (int reg = 0; reg < 4; ++reg) {
                int i = w * 16 + quad * 4 + reg;
                int x = min(max((int)floorf(cwf[i * 6 + cc] - cj) + off, 0), hi);
                atomicAdd(&dbuf[i * DBS + x], lg[tt][reg]);
            }
        }
    };
    auto zeroOwn = [&]() {
        float* rb = &dbuf[w * 16 * DBS];
        for (int e = lane; e < 16 * DBS; e += 64) rb[e] = 0.f;
    };

    stageTbl(qxt + h * 32, 120, 128);
    __syncthreads();

    // ---- bias_q xyz: wave-private ----
    tgemmC(q_s, 0, 40); LFENCE();
    gatherC(0, 20, 39); LFENCE();
    tgemmC(q_s, 1, 40); LFENCE();
    gatherC(1, 20, 39); LFENCE();
    tgemmC(q_s, 2, 40);
    __syncthreads();                       // all waves done reading tbl(qxt)
    gatherC(2, 20, 39);
    stageTbl(qrt + h * 32, 96, 96);
    __syncthreads();
    // ---- bias_q rgb ----
    tgemmC(q_s, 0, 32); LFENCE();
    gatherC(3, 16, 31); LFENCE();
    tgemmC(q_s, 1, 32); LFENCE();
    gatherC(4, 16, 31); LFENCE();
    tgemmC(q_s, 2, 32);
    __syncthreads();                       // tbl/q_s regions go dead here
    gatherC(5, 16, 31);
    stageVtbl(vxt + h * 32, 120);
    stageVt();
    __syncthreads();

    // ---- softmax ----
#pragma unroll
    for (int reg = 0; reg < 4; ++reg) {
        float m = fmaxf(fmaxf(lg[0][reg], lg[1][reg]), fmaxf(lg[2][reg], lg[3][reg]));
        m = fmaxf(m, __shfl_xor(m, 1));
        m = fmaxf(m, __shfl_xor(m, 2));
        m = fmaxf(m, __shfl_xor(m, 4));
        m = fmaxf(m, __shfl_xor(m, 8));
        float s = 0.f;
#pragma unroll
        for (int tt = 0; tt < 4; ++tt) { lg[tt][reg] = __expf(lg[tt][reg] - m); s += lg[tt][reg]; }
        s += __shfl_xor(s, 1); s += __shfl_xor(s, 2);
        s += __shfl_xor(s, 4); s += __shfl_xor(s, 8);
        float inv = 1.f / s;
#pragma unroll
        for (int tt = 0; tt < 4; ++tt) lg[tt][reg] *= inv;
    }
#pragma unroll
    for (int tt = 0; tt < 4; ++tt)
#pragma unroll
        for (int reg = 0; reg < 4; ++reg)
            attn_s[(w * 16 + quad * 4 + reg) * 72 + tt * 16 + l4] = f2bf(lg[tt][reg]);
    zeroOwn();
    __syncthreads();

    // ---- AV ----
    f32x4 acc0 = {0.f, 0.f, 0.f, 0.f}, acc1 = {0.f, 0.f, 0.f, 0.f};
#pragma unroll
    for (int s = 0; s < 2; ++s) {
        short8 af = *(const short8*)&attn_s[(w * 16 + l4) * 72 + s * 32 + quad * 8];
        short8 b0 = *(const short8*)&v_t[l4 * 72 + s * 32 + quad * 8];
        short8 b1 = *(const short8*)&v_t[(16 + l4) * 72 + s * 32 + quad * 8];
        acc0 = __builtin_amdgcn_mfma_f32_16x16x32_bf16(af, b0, acc0, 0, 0, 0);
        acc1 = __builtin_amdgcn_mfma_f32_16x16x32_bf16(af, b1, acc1, 0, 0, 0);
    }

    auto atgemmC = [&](int c, int T, int S) {
#pragma unroll
        for (int s = 0; s < S; ++s) {
            int koff = s * 32 + quad * 8;
            short8 af = {0, 0, 0, 0, 0, 0, 0, 0};
            int kr = 0;
            if (koff < T) {
                const float* ap = &dbuf[(w * 16 + l4) * DBS + koff];
#pragma unroll
                for (int ii = 0; ii < 8; ++ii) af[ii] = (short)f2bf(ap[ii]);
                kr = c * T + koff;
            }
            short8 b0 = *(const short8*)&vtbl[l4 * 136 + kr];
            short8 b1 = *(const short8*)&vtbl[(16 + l4) * 136 + kr];
            acc0 = __builtin_amdgcn_mfma_f32_16x16x32_bf16(af, b0, acc0, 0, 0, 0);
            acc1 = __builtin_amdgcn_mfma_f32_16x16x32_bf16(af, b1, acc1, 0, 0, 0);
        }
    };

    // ---- value-bias xyz: all dbuf traffic wave-private -> fences only ----
    scatterC(0, 20, 39); LFENCE();
    atgemmC(0, 40, 2); LFENCE();
    zeroOwn(); LFENCE();
    scatterC(1, 20, 39); LFENCE();
    atgemmC(1, 40, 2); LFENCE();
    zeroOwn(); LFENCE();
    scatterC(2, 20, 39); LFENCE();
    atgemmC(2, 40, 2);
    __syncthreads();                       // all waves done reading vtbl(vxt)
    zeroOwn();
    stageVtbl(vrt + h * 32, 96);
    __syncthreads();

    // ---- value-bias rgb ----
    scatterC(3, 16, 31); LFENCE();
    atgemmC(0, 32, 1); LFENCE();
    zeroOwn(); LFENCE();
    scatterC(4, 16, 31); LFENCE();
    atgemmC(1, 32, 1); LFENCE();
    zeroOwn(); LFENCE();
    scatterC(5, 16, 31); LFENCE();
    atgemmC(2, 32, 1);

    // ---- epilogue: bf16 ao[i][h*32+d] ----
    {
        ushort* op = aout + (size_t)(n * 64 + w * 16 + quad * 4) * 256 + h * 32;
#pragma unroll
        for (int reg = 0; reg < 4; ++reg) {
            op[reg * 256 + l4] = f2bf(acc0[reg]);
            op[reg * 256 + 16 + l4] = f2bf(acc1[reg]);
        }
    }
}

// ---------------------------------------------------------------------------
// Proj GEMM (bf16 MFMA): out = ao(bf16) @ proj_w(fp32, cast inline)^T + pb
// ---------------------------------------------------------------------------
__global__ __launch_bounds__(256) void k_proj(
    const ushort* __restrict__ A, const float* __restrict__ B,
    const float* __restrict__ bias, float* __restrict__ out)
{
    __shared__ __align__(16) ushort a_s[128 * 72];
    __shared__ __align__(16) ushort b_s[64 * 72];
    const int tid = threadIdx.x;
    const int m0 = blockIdx.y * 128;
    const int n0 = blockIdx.x * 64;
    const int w = tid >> 6, wm = w >> 1, wn = w & 1;
    const int l4 = tid & 15, quad = (tid >> 4) & 3;
    f32x4 acc[4][2];
#pragma unroll
    for (int mt = 0; mt < 4; ++mt)
#pragma unroll
        for (int nt = 0; nt < 2; ++nt) acc[mt][nt] = (f32x4){0.f, 0.f, 0.f, 0.f};

    for (int k0 = 0; k0 < 256; k0 += 64) {
#pragma unroll
        for (int l = 0; l < 4; ++l) {
            int e = tid + l * 256;
            int row = e >> 3, kq = e & 7;
            *(uint4*)&a_s[row * 72 + kq * 8] =
                *(const uint4*)(A + (size_t)(m0 + row) * 256 + k0 + kq * 8);
        }
#pragma unroll
        for (int l = 0; l < 2; ++l) {
            int e = tid + l * 256;
            int row = e >> 3, kq = e & 7;
            const float* bp = B + (size_t)(n0 + row) * 256 + k0 + kq * 8;
            float4 v0 = *(const float4*)bp, v1 = *(const float4*)(bp + 4);
            union { ushort u[8]; uint4 v; } pk;
            pk.u[0] = f2bf(v0.x); pk.u[1] = f2bf(v0.y); pk.u[2] = f2bf(v0.z); pk.u[3] = f2bf(v0.w);
            pk.u[4] = f2bf(v1.x); pk.u[5] = f2bf(v1.y); pk.u[6] = f2bf(v1.z); pk.u[7] = f2bf(v1.w);
            *(uint4*)&b_s[row * 72 + kq * 8] = pk.v;
        }
        __syncthreads();
#pragma unroll
        for (int kh = 0; kh < 2; ++kh) {
            short8 bf0 = *(const short8*)&b_s[(wn * 32 + l4) * 72 + kh * 32 + quad * 8];
            short8 bf1 = *(const short8*)&b_s[(wn * 32 + 16 + l4) * 72 + kh * 32 + quad * 8];
#pragma unroll
            for (int mt = 0; mt < 4; ++mt) {
                short8 af = *(const short8*)&a_s[(wm * 64 + mt * 16 + l4) * 72 + kh * 32 + quad * 8];
                acc[mt][0] = __builtin_amdgcn_mfma_f32_16x16x32_bf16(af, bf0, acc[mt][0], 0, 0, 0);
                acc[mt][1] = __builtin_amdgcn_mfma_f32_16x16x32_bf16(af, bf1, acc[mt][1], 0, 0, 0);
            }
        }
        __syncthreads();
    }
#pragma unroll
    for (int nt = 0; nt < 2; ++nt) {
        int c = n0 + wn * 32 + nt * 16 + l4;
        float bv = bias[c];
#pragma unroll
        for (int mt = 0; mt < 4; ++mt) {
            int mbase = m0 + wm * 64 + mt * 16 + quad * 4;
#pragma unroll
            for (int reg = 0; reg < 4; ++reg)
                out[(size_t)(mbase + reg) * 256 + c] = acc[mt][nt][reg] + bv;
        }
    }
}

extern "C" void kernel_launch(void* const* d_in, const int* in_sizes, int n_in,
                              void* d_out, int out_size, void* d_ws, size_t ws_size,
                              hipStream_t stream)
{
    const float* feats = (const float*)d_in[0];
    const float* nco   = (const float*)d_in[1];
    const float* qkvw  = (const float*)d_in[2];
    const float* qkvb  = (const float*)d_in[3];
    const float* qxt   = (const float*)d_in[4];
    const float* kxt   = (const float*)d_in[5];
    const float* vxt   = (const float*)d_in[6];
    const float* qrt   = (const float*)d_in[7];
    const float* krt   = (const float*)d_in[8];
    const float* vrt   = (const float*)d_in[9];
    const float* pw    = (const float*)d_in[10];
    const float* pb    = (const float*)d_in[11];
    float* out = (float*)d_out;

    ushort* qb  = (ushort*)d_ws;                       // [128][8][64][32] bf16, 4 MB
    ushort* kb  = qb + (size_t)2097152;
    ushort* vb  = kb + (size_t)2097152;
    ushort* aob = vb + (size_t)2097152;                // [8192][256] bf16, 4 MB
    float*  lgt = (float*)(aob + (size_t)2097152);     // [1024][64][64] f32, 16.7 MB

    k_qkv<<<dim3(12, 64), 256, 0, stream>>>(feats, qkvw, qkvb, qb, kb, vb);
    k_bias<<<dim3(1024), 256, 0, stream>>>(qb, kb, nco, kxt, krt, lgt);
    k_av<<<dim3(1024), 256, 0, stream>>>(qb, vb, nco, qxt, vxt, qrt, vrt, lgt, aob);
    k_proj<<<dim3(4, 64), 256, 0, stream>>>(aob, pw, pb, out);
}

// Round 6
// 271.924 us; speedup vs baseline: 1.1655x; 1.0095x over previous
//
#include <hip/hip_runtime.h>

// DIM=256 H=8 HD=32 W=64 N=8192 nw=128
// xyz: T=40, off=20, hi=39 ; rgb: T=32, off=16, hi=31
// table element ((c*T+t)*8+h)*32+d == r*256 + h*32 + d, r=c*T+t

typedef __attribute__((ext_vector_type(8))) short short8;
typedef __attribute__((ext_vector_type(4))) float f32x4;

__device__ __forceinline__ unsigned short f2bf(float f) {
    union { float f; unsigned int u; } v; v.f = f;
    unsigned int r = v.u + 0x7FFFu + ((v.u >> 16) & 1u);
    return (unsigned short)(r >> 16);
}

// Wave-local ordering fence: drains this wave's outstanding DS ops.
#define LFENCE() asm volatile("s_waitcnt lgkmcnt(0)" ::: "memory")

// ---------------------------------------------------------------------------
// QKV GEMM (bf16 MFMA), fp32 inputs cast inline during staging. (unchanged)
// ---------------------------------------------------------------------------
__global__ __launch_bounds__(256) void k_qkv(
    const float* __restrict__ A, const float* __restrict__ B,
    const float* __restrict__ bias,
    ushort* __restrict__ qb, ushort* __restrict__ kb, ushort* __restrict__ vb)
{
    __shared__ __align__(16) ushort a_s[128 * 72];
    __shared__ __align__(16) ushort b_s[64 * 72];
    const int tid = threadIdx.x;
    const int m0 = blockIdx.y * 128;
    const int n0 = blockIdx.x * 64;
    const int w = tid >> 6, wm = w >> 1, wn = w & 1;
    const int l4 = tid & 15, quad = (tid >> 4) & 3;
    f32x4 acc[4][2];
#pragma unroll
    for (int mt = 0; mt < 4; ++mt)
#pragma unroll
        for (int nt = 0; nt < 2; ++nt) acc[mt][nt] = (f32x4){0.f, 0.f, 0.f, 0.f};

    for (int k0 = 0; k0 < 256; k0 += 64) {
#pragma unroll
        for (int l = 0; l < 4; ++l) {
            int e = tid + l * 256;
            int row = e >> 3, kq = e & 7;
            const float* ap = A + (size_t)(m0 + row) * 256 + k0 + kq * 8;
            float4 v0 = *(const float4*)ap, v1 = *(const float4*)(ap + 4);
            union { ushort u[8]; uint4 v; } pk;
            pk.u[0] = f2bf(v0.x); pk.u[1] = f2bf(v0.y); pk.u[2] = f2bf(v0.z); pk.u[3] = f2bf(v0.w);
            pk.u[4] = f2bf(v1.x); pk.u[5] = f2bf(v1.y); pk.u[6] = f2bf(v1.z); pk.u[7] = f2bf(v1.w);
            *(uint4*)&a_s[row * 72 + kq * 8] = pk.v;
        }
#pragma unroll
        for (int l = 0; l < 2; ++l) {
            int e = tid + l * 256;
            int row = e >> 3, kq = e & 7;
            const float* bp = B + (size_t)(n0 + row) * 256 + k0 + kq * 8;
            float4 v0 = *(const float4*)bp, v1 = *(const float4*)(bp + 4);
            union { ushort u[8]; uint4 v; } pk;
            pk.u[0] = f2bf(v0.x); pk.u[1] = f2bf(v0.y); pk.u[2] = f2bf(v0.z); pk.u[3] = f2bf(v0.w);
            pk.u[4] = f2bf(v1.x); pk.u[5] = f2bf(v1.y); pk.u[6] = f2bf(v1.z); pk.u[7] = f2bf(v1.w);
            *(uint4*)&b_s[row * 72 + kq * 8] = pk.v;
        }
        __syncthreads();
#pragma unroll
        for (int kh = 0; kh < 2; ++kh) {
            short8 bf0 = *(const short8*)&b_s[(wn * 32 + l4) * 72 + kh * 32 + quad * 8];
            short8 bf1 = *(const short8*)&b_s[(wn * 32 + 16 + l4) * 72 + kh * 32 + quad * 8];
#pragma unroll
            for (int mt = 0; mt < 4; ++mt) {
                short8 af = *(const short8*)&a_s[(wm * 64 + mt * 16 + l4) * 72 + kh * 32 + quad * 8];
                acc[mt][0] = __builtin_amdgcn_mfma_f32_16x16x32_bf16(af, bf0, acc[mt][0], 0, 0, 0);
                acc[mt][1] = __builtin_amdgcn_mfma_f32_16x16x32_bf16(af, bf1, acc[mt][1], 0, 0, 0);
            }
        }
        __syncthreads();
    }
#pragma unroll
    for (int nt = 0; nt < 2; ++nt) {
        int c = n0 + wn * 32 + nt * 16 + l4;
        float bv = bias[c];
        int s = c >> 8, rem = c & 255, h = rem >> 5, d = rem & 31;
        ushort* dst = (s == 0) ? qb : ((s == 1) ? kb : vb);
        float mul = (s == 0) ? 0.17677669529663687f : 1.0f;
#pragma unroll
        for (int mt = 0; mt < 4; ++mt) {
            int mbase = m0 + wm * 64 + mt * 16 + quad * 4;
#pragma unroll
            for (int reg = 0; reg < 4; ++reg) {
                int m = mbase + reg;
                int nw = m >> 6, ii = m & 63;
                dst[((size_t)((nw * 8 + h) * 64 + ii)) * 32 + d] = f2bf((acc[mt][nt][reg] + bv) * mul);
            }
        }
    }
}

// ---------------------------------------------------------------------------
// Round-14: break the LDS dependency chains.
//
// r5 localization: rear half (bias_q + softmax + AV + value-bias) = ~155 us,
// invariant across occupancy/structure changes; front half = 15 us with the
// SAME phase skeleton. Per-block path 206k cycles vs ~20k of DS throughput:
// latency-chained addressing (cwf LDS read -> addr -> dbuf access, x12 call
// sites) + 96 scalar atgemm reads is the only mechanism that scales.
// Fix: (1) precompute ALL 96 bin indices ONCE into 24 packed u32 VGPRs
// (idxp[c*4+tt], byte reg) — gathers/scatters become single-wait batches of
// independent DS ops; (2) DBS 41->44 (16B-aligned rows) -> atgemm reads as
// 2x f32x4; lgt load as 4x f32x4; zeroOwn float4.
// Register budget: 80 arch (r5) + 24 idx + slack -> ~110-130; total w/ acc
// ~<= 210 < 256 (2 waves/SIMD unchanged — this round attacks latency, not
// occupancy). Spill tripwire: VGPR_Count > 150 or WRITE_SIZE >> 4 MB.
// Falsification: k_av >= 140 us -> chain theory wrong -> replicate bins x4.
// ---------------------------------------------------------------------------
#define DBS 44

__global__ __launch_bounds__(256, 2) void k_bias(
    const ushort* __restrict__ qb, const ushort* __restrict__ kb,
    const float* __restrict__ nco,
    const float* __restrict__ kxt, const float* __restrict__ krt,
    float* __restrict__ lgt)
{
    __shared__ __align__(16) float dbuf[64 * DBS];    // 11,264 B
    __shared__ __align__(16) ushort q_s[64 * 40];     //  5,120 B
    __shared__ __align__(16) ushort k_s[64 * 40];     //  5,120 B
    __shared__ __align__(16) ushort tbl[128 * 40];    // 10,240 B
    __shared__ __align__(16) float cwf[64 * 6];       //  1,536 B  (33.3 KB total)

    const int tid = threadIdx.x;
    const int n = blockIdx.x >> 3;
    const int h = blockIdx.x & 7;
    const int w = tid >> 6;
    const int l4 = tid & 15;
    const int quad = (tid >> 4) & 3;

    const size_t base = (size_t)((n * 8 + h) * 64) * 32;

    {
        int row = tid >> 2, part = tid & 3;
        *(uint4*)&q_s[row * 40 + part * 8] = *(const uint4*)(qb + base + tid * 8);
        *(uint4*)&k_s[row * 40 + part * 8] = *(const uint4*)(kb + base + tid * 8);
    }
    if (tid < 64) {
        const float* cp = nco + (size_t)(n * 64 + tid) * 6;
        cwf[tid * 6 + 0] = cp[0] * 4.f; cwf[tid * 6 + 1] = cp[1] * 4.f;
        cwf[tid * 6 + 2] = cp[2] * 4.f; cwf[tid * 6 + 3] = cp[3] * 8.f;
        cwf[tid * 6 + 4] = cp[4] * 8.f; cwf[tid * 6 + 5] = cp[5] * 8.f;
    }

    auto stageTbl = [&](const float* tbg, int R, int Rpad) {
        for (int e = tid; e < R * 4; e += 256) {
            int r = e >> 2, part = e & 3;
            const float* src = tbg + (size_t)r * 256 + part * 8;
            float4 f0 = *(const float4*)src, f1 = *(const float4*)(src + 4);
            union { ushort u[8]; uint4 v; } pk;
            pk.u[0] = f2bf(f0.x); pk.u[1] = f2bf(f0.y); pk.u[2] = f2bf(f0.z); pk.u[3] = f2bf(f0.w);
            pk.u[4] = f2bf(f1.x); pk.u[5] = f2bf(f1.y); pk.u[6] = f2bf(f1.z); pk.u[7] = f2bf(f1.w);
            *(uint4*)&tbl[r * 40 + part * 8] = pk.v;
        }
        for (int e = tid; e < (Rpad - R) * 40; e += 256) tbl[R * 40 + e] = 0;
    };

    float lg[4][4];   // TRANSPOSED: row j = w*16+quad*4+reg, col i = tt*16+l4
    int ibase[4];
#pragma unroll
    for (int r = 0; r < 4; ++r) ibase[r] = (w * 16 + quad * 4 + r) * DBS;

    auto tgemmC = [&](const ushort* a_s, int c, int T) {
        short8 af = *(const short8*)&a_s[(w * 16 + l4) * 40 + quad * 8];
        const int NT = (T == 40) ? 3 : 2;
        for (int tt = 0; tt < NT; ++tt) {
            short8 bf = *(const short8*)&tbl[(c * T + tt * 16 + l4) * 40 + quad * 8];
            f32x4 a = {0.f, 0.f, 0.f, 0.f};
            a = __builtin_amdgcn_mfma_f32_16x16x32_bf16(af, bf, a, 0, 0, 0);
            int col = tt * 16 + l4;
            int rb = w * 16 + quad * 4;
            if (col < T) {
                dbuf[(rb + 0) * DBS + col] = a[0];
                dbuf[(rb + 1) * DBS + col] = a[1];
                dbuf[(rb + 2) * DBS + col] = a[2];
                dbuf[(rb + 3) * DBS + col] = a[3];
            }
        }
    };

    stageTbl(kxt + h * 32, 120, 128);
    __syncthreads();

    // ---- precompute packed bin indices: x = floor(c_col_i - c_own_j) + off ----
    unsigned idxp[24];
    {
        float co[4][6], cl[4][6];
#pragma unroll
        for (int r = 0; r < 4; ++r) {
            int j = w * 16 + quad * 4 + r;
#pragma unroll
            for (int c6 = 0; c6 < 6; ++c6) co[r][c6] = cwf[j * 6 + c6];
        }
#pragma unroll
        for (int tt = 0; tt < 4; ++tt) {
            int i = tt * 16 + l4;
#pragma unroll
            for (int c6 = 0; c6 < 6; ++c6) cl[tt][c6] = cwf[i * 6 + c6];
        }
#pragma unroll
        for (int c6 = 0; c6 < 6; ++c6) {
            const int off = (c6 < 3) ? 20 : 16, hi = (c6 < 3) ? 39 : 31;
#pragma unroll
            for (int tt = 0; tt < 4; ++tt) {
                unsigned p = 0;
#pragma unroll
                for (int r = 0; r < 4; ++r) {
                    int x = min(max((int)floorf(cl[tt][c6] - co[r][c6]) + off, 0), hi);
                    p |= (unsigned)x << (8 * r);
                }
                idxp[c6 * 4 + tt] = p;
            }
        }
    }

    auto gatherT = [&](int cc) {
#pragma unroll
        for (int tt = 0; tt < 4; ++tt) {
            unsigned p = idxp[cc * 4 + tt];
#pragma unroll
            for (int r = 0; r < 4; ++r) {
                int x = (p >> (8 * r)) & 255;
                lg[tt][r] += dbuf[ibase[r] + x];
            }
        }
    };

    // ---- logitsT = K.Q^T (output rows = k-row j, wave-private) ----
    {
        short8 ak = *(const short8*)&k_s[(w * 16 + l4) * 40 + quad * 8];
#pragma unroll
        for (int tt = 0; tt < 4; ++tt) {
            short8 bq = *(const short8*)&q_s[(tt * 16 + l4) * 40 + quad * 8];
            f32x4 r = {0.f, 0.f, 0.f, 0.f};
            r = __builtin_amdgcn_mfma_f32_16x16x32_bf16(ak, bq, r, 0, 0, 0);
            lg[tt][0] = r[0]; lg[tt][1] = r[1]; lg[tt][2] = r[2]; lg[tt][3] = r[3];
        }
    }

    // ---- bias_k xyz: all wave-private ----
    tgemmC(k_s, 0, 40); LFENCE();
    gatherT(0); LFENCE();
    tgemmC(k_s, 1, 40); LFENCE();
    gatherT(1); LFENCE();
    tgemmC(k_s, 2, 40); LFENCE();
    gatherT(2);
    __syncthreads();                       // all waves done reading tbl(kxt)
    stageTbl(krt + h * 32, 96, 96);
    __syncthreads();
    // ---- bias_k rgb ----
    tgemmC(k_s, 0, 32); LFENCE();
    gatherT(3); LFENCE();
    tgemmC(k_s, 1, 32); LFENCE();
    gatherT(4); LFENCE();
    tgemmC(k_s, 2, 32); LFENCE();
    gatherT(5);

    // ---- store logitsT f32: lgt[nh][j][i] ----
    {
        float* lp = lgt + (size_t)(n * 8 + h) * 4096;
#pragma unroll
        for (int tt = 0; tt < 4; ++tt)
#pragma unroll
            for (int reg = 0; reg < 4; ++reg)
                lp[(w * 16 + quad * 4 + reg) * 64 + tt * 16 + l4] = lg[tt][reg];
    }
}

__global__ __launch_bounds__(256, 2) void k_av(
    const ushort* __restrict__ qb, const ushort* __restrict__ vb,
    const float* __restrict__ nco,
    const float* __restrict__ qxt, const float* __restrict__ vxt,
    const float* __restrict__ qrt, const float* __restrict__ vrt,
    const float* __restrict__ lgt,
    ushort* __restrict__ aout)
{
    __shared__ __align__(16) float dbuf[64 * DBS];   // 11,264 B
    __shared__ __align__(16) ushort U[11264];        // 22,528 B overlay region
    __shared__ __align__(16) float cwf[64 * 6];      //  1,536 B (35.3 KB total)
    // Phase A overlays:
    ushort* q_s  = U;              // [64][40] = 2560 ushorts
    ushort* tbl  = U + 2560;       // [128][40] = 5120 ushorts, ends 7680
    // Phase B overlays:
    ushort* attn_s = U;            // [64][72] = 4608 ushorts
    ushort* v_t    = U + 4608;     // [32][72] = 2304, ends 6912
    ushort* vtbl   = U + 6912;     // [32][136] = 4352, ends 11264

    const int tid = threadIdx.x;
    const int n = blockIdx.x >> 3;
    const int h = blockIdx.x & 7;
    const int w = tid >> 6;
    const int lane = tid & 63;
    const int l4 = tid & 15;
    const int quad = (tid >> 4) & 3;

    const size_t base = (size_t)((n * 8 + h) * 64) * 32;

    {
        int row = tid >> 2, part = tid & 3;
        *(uint4*)&q_s[row * 40 + part * 8] = *(const uint4*)(qb + base + tid * 8);
    }
    if (tid < 64) {
        const float* cp = nco + (size_t)(n * 64 + tid) * 6;
        cwf[tid * 6 + 0] = cp[0] * 4.f; cwf[tid * 6 + 1] = cp[1] * 4.f;
        cwf[tid * 6 + 2] = cp[2] * 4.f; cwf[tid * 6 + 3] = cp[3] * 8.f;
        cwf[tid * 6 + 4] = cp[4] * 8.f; cwf[tid * 6 + 5] = cp[5] * 8.f;
    }

    auto stageTbl = [&](const float* tbg, int R, int Rpad) {
        for (int e = tid; e < R * 4; e += 256) {
            int r = e >> 2, part = e & 3;
            const float* src = tbg + (size_t)r * 256 + part * 8;
            float4 f0 = *(const float4*)src, f1 = *(const float4*)(src + 4);
            union { ushort u[8]; uint4 v; } pk;
            pk.u[0] = f2bf(f0.x); pk.u[1] = f2bf(f0.y); pk.u[2] = f2bf(f0.z); pk.u[3] = f2bf(f0.w);
            pk.u[4] = f2bf(f1.x); pk.u[5] = f2bf(f1.y); pk.u[6] = f2bf(f1.z); pk.u[7] = f2bf(f1.w);
            *(uint4*)&tbl[r * 40 + part * 8] = pk.v;
        }
        for (int e = tid; e < (Rpad - R) * 40; e += 256) tbl[R * 40 + e] = 0;
    };
    auto stageVtbl = [&](const float* tbg, int R) {
        for (int e = tid; e < R * 4; e += 256) {
            int r = e >> 2, part = e & 3;
            const float* src = tbg + (size_t)r * 256 + part * 8;
            float4 f0 = *(const float4*)src, f1 = *(const float4*)(src + 4);
            int d0 = part * 8;
            vtbl[(d0 + 0) * 136 + r] = f2bf(f0.x);
            vtbl[(d0 + 1) * 136 + r] = f2bf(f0.y);
            vtbl[(d0 + 2) * 136 + r] = f2bf(f0.z);
            vtbl[(d0 + 3) * 136 + r] = f2bf(f0.w);
            vtbl[(d0 + 4) * 136 + r] = f2bf(f1.x);
            vtbl[(d0 + 5) * 136 + r] = f2bf(f1.y);
            vtbl[(d0 + 6) * 136 + r] = f2bf(f1.z);
            vtbl[(d0 + 7) * 136 + r] = f2bf(f1.w);
        }
    };
    auto stageVt = [&]() {
        int j = tid >> 2, d0 = (tid & 3) * 8;
        uint4 pk = *(const uint4*)(vb + base + tid * 8);
        const ushort* u = (const ushort*)&pk;
#pragma unroll
        for (int ii = 0; ii < 8; ++ii) v_t[(d0 + ii) * 72 + j] = u[ii];
    };

    // ---- load logitsT transposed into lg[i own-row][j col] (f32x4) ----
    float lg[4][4];
    {
        const float* lp = lgt + (size_t)(n * 8 + h) * 4096;
        int i0 = w * 16 + quad * 4;
#pragma unroll
        for (int tt = 0; tt < 4; ++tt) {
            f32x4 v = *(const f32x4*)(lp + (size_t)(tt * 16 + l4) * 64 + i0);
            lg[tt][0] = v[0]; lg[tt][1] = v[1]; lg[tt][2] = v[2]; lg[tt][3] = v[3];
        }
    }

    int ibase[4];
#pragma unroll
    for (int r = 0; r < 4; ++r) ibase[r] = (w * 16 + quad * 4 + r) * DBS;

    auto tgemmC = [&](const ushort* a_s, int c, int T) {
        short8 af = *(const short8*)&a_s[(w * 16 + l4) * 40 + quad * 8];
        const int NT = (T == 40) ? 3 : 2;
        for (int tt = 0; tt < NT; ++tt) {
            short8 bf = *(const short8*)&tbl[(c * T + tt * 16 + l4) * 40 + quad * 8];
            f32x4 a = {0.f, 0.f, 0.f, 0.f};
            a = __builtin_amdgcn_mfma_f32_16x16x32_bf16(af, bf, a, 0, 0, 0);
            int col = tt * 16 + l4;
            int rb = w * 16 + quad * 4;
            if (col < T) {
                dbuf[(rb + 0) * DBS + col] = a[0];
                dbuf[(rb + 1) * DBS + col] = a[1];
                dbuf[(rb + 2) * DBS + col] = a[2];
                dbuf[(rb + 3) * DBS + col] = a[3];
            }
        }
    };
    auto zeroOwn = [&]() {
        float4 z = {0.f, 0.f, 0.f, 0.f};
        float4* rb = (float4*)&dbuf[w * 16 * DBS];     // 16*44 = 704 f = 176 f4
        for (int v = lane; v < 176; v += 64) rb[v] = z;
    };

    stageTbl(qxt + h * 32, 120, 128);
    __syncthreads();

    // ---- precompute packed bin indices: x = floor(c_own_i - c_col_j) + off ----
    unsigned idxp[24];
    {
        float co[4][6], cl[4][6];
#pragma unroll
        for (int r = 0; r < 4; ++r) {
            int i = w * 16 + quad * 4 + r;
#pragma unroll
            for (int c6 = 0; c6 < 6; ++c6) co[r][c6] = cwf[i * 6 + c6];
        }
#pragma unroll
        for (int tt = 0; tt < 4; ++tt) {
            int j = tt * 16 + l4;
#pragma unroll
            for (int c6 = 0; c6 < 6; ++c6) cl[tt][c6] = cwf[j * 6 + c6];
        }
#pragma unroll
        for (int c6 = 0; c6 < 6; ++c6) {
            const int off = (c6 < 3) ? 20 : 16, hi = (c6 < 3) ? 39 : 31;
#pragma unroll
            for (int tt = 0; tt < 4; ++tt) {
                unsigned p = 0;
#pragma unroll
                for (int r = 0; r < 4; ++r) {
                    int x = min(max((int)floorf(co[r][c6] - cl[tt][c6]) + off, 0), hi);
                    p |= (unsigned)x << (8 * r);
                }
                idxp[c6 * 4 + tt] = p;
            }
        }
    }

    auto gatherC = [&](int cc) {
#pragma unroll
        for (int tt = 0; tt < 4; ++tt) {
            unsigned p = idxp[cc * 4 + tt];
#pragma unroll
            for (int r = 0; r < 4; ++r) {
                int x = (p >> (8 * r)) & 255;
                lg[tt][r] += dbuf[ibase[r] + x];
            }
        }
    };
    auto scatterC = [&](int cc) {
#pragma unroll
        for (int tt = 0; tt < 4; ++tt) {
            unsigned p = idxp[cc * 4 + tt];
#pragma unroll
            for (int r = 0; r < 4; ++r) {
                int x = (p >> (8 * r)) & 255;
                atomicAdd(&dbuf[ibase[r] + x], lg[tt][r]);
            }
        }
    };

    // ---- bias_q xyz: wave-private ----
    tgemmC(q_s, 0, 40); LFENCE();
    gatherC(0); LFENCE();
    tgemmC(q_s, 1, 40); LFENCE();
    gatherC(1); LFENCE();
    tgemmC(q_s, 2, 40);
    __syncthreads();                       // all waves done reading tbl(qxt)
    gatherC(2);
    stageTbl(qrt + h * 32, 96, 96);
    __syncthreads();
    // ---- bias_q rgb ----
    tgemmC(q_s, 0, 32); LFENCE();
    gatherC(3); LFENCE();
    tgemmC(q_s, 1, 32); LFENCE();
    gatherC(4); LFENCE();
    tgemmC(q_s, 2, 32);
    __syncthreads();                       // tbl/q_s regions go dead here
    gatherC(5);
    stageVtbl(vxt + h * 32, 120);
    stageVt();
    __syncthreads();

    // ---- softmax ----
#pragma unroll
    for (int reg = 0; reg < 4; ++reg) {
        float m = fmaxf(fmaxf(lg[0][reg], lg[1][reg]), fmaxf(lg[2][reg], lg[3][reg]));
        m = fmaxf(m, __shfl_xor(m, 1));
        m = fmaxf(m, __shfl_xor(m, 2));
        m = fmaxf(m, __shfl_xor(m, 4));
        m = fmaxf(m, __shfl_xor(m, 8));
        float s = 0.f;
#pragma unroll
        for (int tt = 0; tt < 4; ++tt) { lg[tt][reg] = __expf(lg[tt][reg] - m); s += lg[tt][reg]; }
        s += __shfl_xor(s, 1); s += __shfl_xor(s, 2);
        s += __shfl_xor(s, 4); s += __shfl_xor(s, 8);
        float inv = 1.f / s;
#pragma unroll
        for (int tt = 0; tt < 4; ++tt) lg[tt][reg] *= inv;
    }
#pragma unroll
    for (int tt = 0; tt < 4; ++tt)
#pragma unroll
        for (int reg = 0; reg < 4; ++reg)
            attn_s[(w * 16 + quad * 4 + reg) * 72 + tt * 16 + l4] = f2bf(lg[tt][reg]);
    zeroOwn();
    __syncthreads();

    // ---- AV ----
    f32x4 acc0 = {0.f, 0.f, 0.f, 0.f}, acc1 = {0.f, 0.f, 0.f, 0.f};
#pragma unroll
    for (int s = 0; s < 2; ++s) {
        short8 af = *(const short8*)&attn_s[(w * 16 + l4) * 72 + s * 32 + quad * 8];
        short8 b0 = *(const short8*)&v_t[l4 * 72 + s * 32 + quad * 8];
        short8 b1 = *(const short8*)&v_t[(16 + l4) * 72 + s * 32 + quad * 8];
        acc0 = __builtin_amdgcn_mfma_f32_16x16x32_bf16(af, b0, acc0, 0, 0, 0);
        acc1 = __builtin_amdgcn_mfma_f32_16x16x32_bf16(af, b1, acc1, 0, 0, 0);
    }

    auto atgemmC = [&](int c, int T, int S) {
#pragma unroll
        for (int s = 0; s < S; ++s) {
            int koff = s * 32 + quad * 8;
            short8 af = {0, 0, 0, 0, 0, 0, 0, 0};
            int kr = 0;
            if (koff < T) {
                const float* ap = &dbuf[(w * 16 + l4) * DBS + koff];
                f32x4 v0 = *(const f32x4*)ap;
                f32x4 v1 = *(const f32x4*)(ap + 4);
                af[0] = (short)f2bf(v0[0]); af[1] = (short)f2bf(v0[1]);
                af[2] = (short)f2bf(v0[2]); af[3] = (short)f2bf(v0[3]);
                af[4] = (short)f2bf(v1[0]); af[5] = (short)f2bf(v1[1]);
                af[6] = (short)f2bf(v1[2]); af[7] = (short)f2bf(v1[3]);
                kr = c * T + koff;
            }
            short8 b0 = *(const short8*)&vtbl[l4 * 136 + kr];
            short8 b1 = *(const short8*)&vtbl[(16 + l4) * 136 + kr];
            acc0 = __builtin_amdgcn_mfma_f32_16x16x32_bf16(af, b0, acc0, 0, 0, 0);
            acc1 = __builtin_amdgcn_mfma_f32_16x16x32_bf16(af, b1, acc1, 0, 0, 0);
        }
    };

    // ---- value-bias xyz: all dbuf traffic wave-private -> fences only ----
    scatterC(0); LFENCE();
    atgemmC(0, 40, 2); LFENCE();
    zeroOwn(); LFENCE();
    scatterC(1); LFENCE();
    atgemmC(1, 40, 2); LFENCE();
    zeroOwn(); LFENCE();
    scatterC(2); LFENCE();
    atgemmC(2, 40, 2);
    __syncthreads();                       // all waves done reading vtbl(vxt)
    zeroOwn();
    stageVtbl(vrt + h * 32, 96);
    __syncthreads();

    // ---- value-bias rgb ----
    scatterC(3); LFENCE();
    atgemmC(0, 32, 1); LFENCE();
    zeroOwn(); LFENCE();
    scatterC(4); LFENCE();
    atgemmC(1, 32, 1); LFENCE();
    zeroOwn(); LFENCE();
    scatterC(5); LFENCE();
    atgemmC(2, 32, 1);

    // ---- epilogue: bf16 ao[i][h*32+d] ----
    {
        ushort* op = aout + (size_t)(n * 64 + w * 16 + quad * 4) * 256 + h * 32;
#pragma unroll
        for (int reg = 0; reg < 4; ++reg) {
            op[reg * 256 + l4] = f2bf(acc0[reg]);
            op[reg * 256 + 16 + l4] = f2bf(acc1[reg]);
        }
    }
}

// ---------------------------------------------------------------------------
// Proj GEMM (bf16 MFMA): out = ao(bf16) @ proj_w(fp32, cast inline)^T + pb
// ---------------------------------------------------------------------------
__global__ __launch_bounds__(256) void k_proj(
    const ushort* __restrict__ A, const float* __restrict__ B,
    const float* __restrict__ bias, float* __restrict__ out)
{
    __shared__ __align__(16) ushort a_s[128 * 72];
    __shared__ __align__(16) ushort b_s[64 * 72];
    const int tid = threadIdx.x;
    const int m0 = blockIdx.y * 128;
    const int n0 = blockIdx.x * 64;
    const int w = tid >> 6, wm = w >> 1, wn = w & 1;
    const int l4 = tid & 15, quad = (tid >> 4) & 3;
    f32x4 acc[4][2];
#pragma unroll
    for (int mt = 0; mt < 4; ++mt)
#pragma unroll
        for (int nt = 0; nt < 2; ++nt) acc[mt][nt] = (f32x4){0.f, 0.f, 0.f, 0.f};

    for (int k0 = 0; k0 < 256; k0 += 64) {
#pragma unroll
        for (int l = 0; l < 4; ++l) {
            int e = tid + l * 256;
            int row = e >> 3, kq = e & 7;
            *(uint4*)&a_s[row * 72 + kq * 8] =
                *(const uint4*)(A + (size_t)(m0 + row) * 256 + k0 + kq * 8);
        }
#pragma unroll
        for (int l = 0; l < 2; ++l) {
            int e = tid + l * 256;
            int row = e >> 3, kq = e & 7;
            const float* bp = B + (size_t)(n0 + row) * 256 + k0 + kq * 8;
            float4 v0 = *(const float4*)bp, v1 = *(const float4*)(bp + 4);
            union { ushort u[8]; uint4 v; } pk;
            pk.u[0] = f2bf(v0.x); pk.u[1] = f2bf(v0.y); pk.u[2] = f2bf(v0.z); pk.u[3] = f2bf(v0.w);
            pk.u[4] = f2bf(v1.x); pk.u[5] = f2bf(v1.y); pk.u[6] = f2bf(v1.z); pk.u[7] = f2bf(v1.w);
            *(uint4*)&b_s[row * 72 + kq * 8] = pk.v;
        }
        __syncthreads();
#pragma unroll
        for (int kh = 0; kh < 2; ++kh) {
            short8 bf0 = *(const short8*)&b_s[(wn * 32 + l4) * 72 + kh * 32 + quad * 8];
            short8 bf1 = *(const short8*)&b_s[(wn * 32 + 16 + l4) * 72 + kh * 32 + quad * 8];
#pragma unroll
            for (int mt = 0; mt < 4; ++mt) {
                short8 af = *(const short8*)&a_s[(wm * 64 + mt * 16 + l4) * 72 + kh * 32 + quad * 8];
                acc[mt][0] = __builtin_amdgcn_mfma_f32_16x16x32_bf16(af, bf0, acc[mt][0], 0, 0, 0);
                acc[mt][1] = __builtin_amdgcn_mfma_f32_16x16x32_bf16(af, bf1, acc[mt][1], 0, 0, 0);
            }
        }
        __syncthreads();
    }
#pragma unroll
    for (int nt = 0; nt < 2; ++nt) {
        int c = n0 + wn * 32 + nt * 16 + l4;
        float bv = bias[c];
#pragma unroll
        for (int mt = 0; mt < 4; ++mt) {
            int mbase = m0 + wm * 64 + mt * 16 + quad * 4;
#pragma unroll
            for (int reg = 0; reg < 4; ++reg)
                out[(size_t)(mbase + reg) * 256 + c] = acc[mt][nt][reg] + bv;
        }
    }
}

extern "C" void kernel_launch(void* const* d_in, const int* in_sizes, int n_in,
                              void* d_out, int out_size, void* d_ws, size_t ws_size,
                              hipStream_t stream)
{
    const float* feats = (const float*)d_in[0];
    const float* nco   = (const float*)d_in[1];
    const float* qkvw  = (const float*)d_in[2];
    const float* qkvb  = (const float*)d_in[3];
    const float* qxt   = (const float*)d_in[4];
    const float* kxt   = (const float*)d_in[5];
    const float* vxt   = (const float*)d_in[6];
    const float* qrt   = (const float*)d_in[7];
    const float* krt   = (const float*)d_in[8];
    const float* vrt   = (const float*)d_in[9];
    const float* pw    = (const float*)d_in[10];
    const float* pb    = (const float*)d_in[11];
    float* out = (float*)d_out;

    ushort* qb  = (ushort*)d_ws;                       // [128][8][64][32] bf16, 4 MB
    ushort* kb  = qb + (size_t)2097152;
    ushort* vb  = kb + (size_t)2097152;
    ushort* aob = vb + (size_t)2097152;                // [8192][256] bf16, 4 MB
    float*  lgt = (float*)(aob + (size_t)2097152);     // [1024][64][64] f32, 16.7 MB

    k_qkv<<<dim3(12, 64), 256, 0, stream>>>(feats, qkvw, qkvb, qb, kb, vb);
    k_bias<<<dim3(1024), 256, 0, stream>>>(qb, kb, nco, kxt, krt, lgt);
    k_av<<<dim3(1024), 256, 0, stream>>>(qb, vb, nco, qxt, vxt, qrt, vrt, lgt, aob);
    k_proj<<<dim3(4, 64), 256, 0, stream>>>(aob, pw, pb, out);
}

// Round 7
// 153.664 us; speedup vs baseline: 2.0624x; 1.7696x over previous
//
#include <hip/hip_runtime.h>

// DIM=256 H=8 HD=32 W=64 N=8192 nw=128
// xyz: T=40, off=20, hi=39 ; rgb: T=32, off=16, hi=31
// table element ((c*T+t)*8+h)*32+d == r*256 + h*32 + d, r=c*T+t

typedef __attribute__((ext_vector_type(8))) short short8;
typedef __attribute__((ext_vector_type(4))) float f32x4;

__device__ __forceinline__ unsigned short f2bf(float f) {
    union { float f; unsigned int u; } v; v.f = f;
    unsigned int r = v.u + 0x7FFFu + ((v.u >> 16) & 1u);
    return (unsigned short)(r >> 16);
}

// Wave-local ordering fence: drains this wave's outstanding DS ops.
#define LFENCE() asm volatile("s_waitcnt lgkmcnt(0)" ::: "memory")

// ---------------------------------------------------------------------------
// QKV GEMM (bf16 MFMA), fp32 inputs cast inline during staging. (unchanged)
// ---------------------------------------------------------------------------
__global__ __launch_bounds__(256) void k_qkv(
    const float* __restrict__ A, const float* __restrict__ B,
    const float* __restrict__ bias,
    ushort* __restrict__ qb, ushort* __restrict__ kb, ushort* __restrict__ vb)
{
    __shared__ __align__(16) ushort a_s[128 * 72];
    __shared__ __align__(16) ushort b_s[64 * 72];
    const int tid = threadIdx.x;
    const int m0 = blockIdx.y * 128;
    const int n0 = blockIdx.x * 64;
    const int w = tid >> 6, wm = w >> 1, wn = w & 1;
    const int l4 = tid & 15, quad = (tid >> 4) & 3;
    f32x4 acc[4][2];
#pragma unroll
    for (int mt = 0; mt < 4; ++mt)
#pragma unroll
        for (int nt = 0; nt < 2; ++nt) acc[mt][nt] = (f32x4){0.f, 0.f, 0.f, 0.f};

    for (int k0 = 0; k0 < 256; k0 += 64) {
#pragma unroll
        for (int l = 0; l < 4; ++l) {
            int e = tid + l * 256;
            int row = e >> 3, kq = e & 7;
            const float* ap = A + (size_t)(m0 + row) * 256 + k0 + kq * 8;
            float4 v0 = *(const float4*)ap, v1 = *(const float4*)(ap + 4);
            union { ushort u[8]; uint4 v; } pk;
            pk.u[0] = f2bf(v0.x); pk.u[1] = f2bf(v0.y); pk.u[2] = f2bf(v0.z); pk.u[3] = f2bf(v0.w);
            pk.u[4] = f2bf(v1.x); pk.u[5] = f2bf(v1.y); pk.u[6] = f2bf(v1.z); pk.u[7] = f2bf(v1.w);
            *(uint4*)&a_s[row * 72 + kq * 8] = pk.v;
        }
#pragma unroll
        for (int l = 0; l < 2; ++l) {
            int e = tid + l * 256;
            int row = e >> 3, kq = e & 7;
            const float* bp = B + (size_t)(n0 + row) * 256 + k0 + kq * 8;
            float4 v0 = *(const float4*)bp, v1 = *(const float4*)(bp + 4);
            union { ushort u[8]; uint4 v; } pk;
            pk.u[0] = f2bf(v0.x); pk.u[1] = f2bf(v0.y); pk.u[2] = f2bf(v0.z); pk.u[3] = f2bf(v0.w);
            pk.u[4] = f2bf(v1.x); pk.u[5] = f2bf(v1.y); pk.u[6] = f2bf(v1.z); pk.u[7] = f2bf(v1.w);
            *(uint4*)&b_s[row * 72 + kq * 8] = pk.v;
        }
        __syncthreads();
#pragma unroll
        for (int kh = 0; kh < 2; ++kh) {
            short8 bf0 = *(const short8*)&b_s[(wn * 32 + l4) * 72 + kh * 32 + quad * 8];
            short8 bf1 = *(const short8*)&b_s[(wn * 32 + 16 + l4) * 72 + kh * 32 + quad * 8];
#pragma unroll
            for (int mt = 0; mt < 4; ++mt) {
                short8 af = *(const short8*)&a_s[(wm * 64 + mt * 16 + l4) * 72 + kh * 32 + quad * 8];
                acc[mt][0] = __builtin_amdgcn_mfma_f32_16x16x32_bf16(af, bf0, acc[mt][0], 0, 0, 0);
                acc[mt][1] = __builtin_amdgcn_mfma_f32_16x16x32_bf16(af, bf1, acc[mt][1], 0, 0, 0);
            }
        }
        __syncthreads();
    }
#pragma unroll
    for (int nt = 0; nt < 2; ++nt) {
        int c = n0 + wn * 32 + nt * 16 + l4;
        float bv = bias[c];
        int s = c >> 8, rem = c & 255, h = rem >> 5, d = rem & 31;
        ushort* dst = (s == 0) ? qb : ((s == 1) ? kb : vb);
        float mul = (s == 0) ? 0.17677669529663687f : 1.0f;
#pragma unroll
        for (int mt = 0; mt < 4; ++mt) {
            int mbase = m0 + wm * 64 + mt * 16 + quad * 4;
#pragma unroll
            for (int reg = 0; reg < 4; ++reg) {
                int m = mbase + reg;
                int nw = m >> 6, ii = m & 63;
                dst[((size_t)((nw * 8 + h) * 64 + ii)) * 32 + d] = f2bf((acc[mt][nt][reg] + bv) * mul);
            }
        }
    }
}

// ---------------------------------------------------------------------------
// Round-15: kill the FP-atomic CAS loops.
//
// r6 post-mortem: idx precompute + vectorization removed VALU (9.9->6.5%)
// but dur flat — chain theory falsified. Missing-mass audit: LDS float
// atomicAdd lowers to a CAS RETRY LOOP (no native fp32 LDS add without
// unsafe-fp-atomics): dependent read->cmpswap->retry ~300cyc/iter, x
// contention (16 lanes/instr into one row's 40 bins). 96 atomic instrs x
// ~4-8 retries ~= the entire unexplained 120-180k cyc/block. Explains the
// r0-r6 invariance (~150us rear half, all kept fp atomics) AND k_bias's
// 15us (zero atomics).
// Fix: fixed-point bins. scatter adds (unsigned)(attn*2^24+0.5) via INTEGER
// atomicAdd -> native ds_add_u32 (HW RMW; collisions ~N/2.8, negligible).
// atgemm reads back (float)u * 2^-24. Row-sum=1 -> bin<=1 -> max 2^24 << 2^32.
// Error <=2e-6, swamped by bf16 (2^-8) quantization of bins.
// Prediction: k_av 164 -> 60-95us. Falsification: >=140us -> atomics
// exonerated -> split rear across 2x blocks (32 rows/block).
// ---------------------------------------------------------------------------
#define DBS 44
#define FXS 16777216.0f
#define FXI (1.0f / 16777216.0f)

__global__ __launch_bounds__(256, 2) void k_bias(
    const ushort* __restrict__ qb, const ushort* __restrict__ kb,
    const float* __restrict__ nco,
    const float* __restrict__ kxt, const float* __restrict__ krt,
    float* __restrict__ lgt)
{
    __shared__ __align__(16) float dbuf[64 * DBS];    // 11,264 B
    __shared__ __align__(16) ushort q_s[64 * 40];     //  5,120 B
    __shared__ __align__(16) ushort k_s[64 * 40];     //  5,120 B
    __shared__ __align__(16) ushort tbl[128 * 40];    // 10,240 B
    __shared__ __align__(16) float cwf[64 * 6];       //  1,536 B  (33.3 KB total)

    const int tid = threadIdx.x;
    const int n = blockIdx.x >> 3;
    const int h = blockIdx.x & 7;
    const int w = tid >> 6;
    const int l4 = tid & 15;
    const int quad = (tid >> 4) & 3;

    const size_t base = (size_t)((n * 8 + h) * 64) * 32;

    {
        int row = tid >> 2, part = tid & 3;
        *(uint4*)&q_s[row * 40 + part * 8] = *(const uint4*)(qb + base + tid * 8);
        *(uint4*)&k_s[row * 40 + part * 8] = *(const uint4*)(kb + base + tid * 8);
    }
    if (tid < 64) {
        const float* cp = nco + (size_t)(n * 64 + tid) * 6;
        cwf[tid * 6 + 0] = cp[0] * 4.f; cwf[tid * 6 + 1] = cp[1] * 4.f;
        cwf[tid * 6 + 2] = cp[2] * 4.f; cwf[tid * 6 + 3] = cp[3] * 8.f;
        cwf[tid * 6 + 4] = cp[4] * 8.f; cwf[tid * 6 + 5] = cp[5] * 8.f;
    }

    auto stageTbl = [&](const float* tbg, int R, int Rpad) {
        for (int e = tid; e < R * 4; e += 256) {
            int r = e >> 2, part = e & 3;
            const float* src = tbg + (size_t)r * 256 + part * 8;
            float4 f0 = *(const float4*)src, f1 = *(const float4*)(src + 4);
            union { ushort u[8]; uint4 v; } pk;
            pk.u[0] = f2bf(f0.x); pk.u[1] = f2bf(f0.y); pk.u[2] = f2bf(f0.z); pk.u[3] = f2bf(f0.w);
            pk.u[4] = f2bf(f1.x); pk.u[5] = f2bf(f1.y); pk.u[6] = f2bf(f1.z); pk.u[7] = f2bf(f1.w);
            *(uint4*)&tbl[r * 40 + part * 8] = pk.v;
        }
        for (int e = tid; e < (Rpad - R) * 40; e += 256) tbl[R * 40 + e] = 0;
    };

    float lg[4][4];   // TRANSPOSED: row j = w*16+quad*4+reg, col i = tt*16+l4
    int ibase[4];
#pragma unroll
    for (int r = 0; r < 4; ++r) ibase[r] = (w * 16 + quad * 4 + r) * DBS;

    auto tgemmC = [&](const ushort* a_s, int c, int T) {
        short8 af = *(const short8*)&a_s[(w * 16 + l4) * 40 + quad * 8];
        const int NT = (T == 40) ? 3 : 2;
        for (int tt = 0; tt < NT; ++tt) {
            short8 bf = *(const short8*)&tbl[(c * T + tt * 16 + l4) * 40 + quad * 8];
            f32x4 a = {0.f, 0.f, 0.f, 0.f};
            a = __builtin_amdgcn_mfma_f32_16x16x32_bf16(af, bf, a, 0, 0, 0);
            int col = tt * 16 + l4;
            int rb = w * 16 + quad * 4;
            if (col < T) {
                dbuf[(rb + 0) * DBS + col] = a[0];
                dbuf[(rb + 1) * DBS + col] = a[1];
                dbuf[(rb + 2) * DBS + col] = a[2];
                dbuf[(rb + 3) * DBS + col] = a[3];
            }
        }
    };

    stageTbl(kxt + h * 32, 120, 128);
    __syncthreads();

    // ---- precompute packed bin indices: x = floor(c_col_i - c_own_j) + off ----
    unsigned idxp[24];
    {
        float co[4][6], cl[4][6];
#pragma unroll
        for (int r = 0; r < 4; ++r) {
            int j = w * 16 + quad * 4 + r;
#pragma unroll
            for (int c6 = 0; c6 < 6; ++c6) co[r][c6] = cwf[j * 6 + c6];
        }
#pragma unroll
        for (int tt = 0; tt < 4; ++tt) {
            int i = tt * 16 + l4;
#pragma unroll
            for (int c6 = 0; c6 < 6; ++c6) cl[tt][c6] = cwf[i * 6 + c6];
        }
#pragma unroll
        for (int c6 = 0; c6 < 6; ++c6) {
            const int off = (c6 < 3) ? 20 : 16, hi = (c6 < 3) ? 39 : 31;
#pragma unroll
            for (int tt = 0; tt < 4; ++tt) {
                unsigned p = 0;
#pragma unroll
                for (int r = 0; r < 4; ++r) {
                    int x = min(max((int)floorf(cl[tt][c6] - co[r][c6]) + off, 0), hi);
                    p |= (unsigned)x << (8 * r);
                }
                idxp[c6 * 4 + tt] = p;
            }
        }
    }

    auto gatherT = [&](int cc) {
#pragma unroll
        for (int tt = 0; tt < 4; ++tt) {
            unsigned p = idxp[cc * 4 + tt];
#pragma unroll
            for (int r = 0; r < 4; ++r) {
                int x = (p >> (8 * r)) & 255;
                lg[tt][r] += dbuf[ibase[r] + x];
            }
        }
    };

    // ---- logitsT = K.Q^T (output rows = k-row j, wave-private) ----
    {
        short8 ak = *(const short8*)&k_s[(w * 16 + l4) * 40 + quad * 8];
#pragma unroll
        for (int tt = 0; tt < 4; ++tt) {
            short8 bq = *(const short8*)&q_s[(tt * 16 + l4) * 40 + quad * 8];
            f32x4 r = {0.f, 0.f, 0.f, 0.f};
            r = __builtin_amdgcn_mfma_f32_16x16x32_bf16(ak, bq, r, 0, 0, 0);
            lg[tt][0] = r[0]; lg[tt][1] = r[1]; lg[tt][2] = r[2]; lg[tt][3] = r[3];
        }
    }

    // ---- bias_k xyz: all wave-private ----
    tgemmC(k_s, 0, 40); LFENCE();
    gatherT(0); LFENCE();
    tgemmC(k_s, 1, 40); LFENCE();
    gatherT(1); LFENCE();
    tgemmC(k_s, 2, 40); LFENCE();
    gatherT(2);
    __syncthreads();                       // all waves done reading tbl(kxt)
    stageTbl(krt + h * 32, 96, 96);
    __syncthreads();
    // ---- bias_k rgb ----
    tgemmC(k_s, 0, 32); LFENCE();
    gatherT(3); LFENCE();
    tgemmC(k_s, 1, 32); LFENCE();
    gatherT(4); LFENCE();
    tgemmC(k_s, 2, 32); LFENCE();
    gatherT(5);

    // ---- store logitsT f32: lgt[nh][j][i] ----
    {
        float* lp = lgt + (size_t)(n * 8 + h) * 4096;
#pragma unroll
        for (int tt = 0; tt < 4; ++tt)
#pragma unroll
            for (int reg = 0; reg < 4; ++reg)
                lp[(w * 16 + quad * 4 + reg) * 64 + tt * 16 + l4] = lg[tt][reg];
    }
}

__global__ __launch_bounds__(256, 2) void k_av(
    const ushort* __restrict__ qb, const ushort* __restrict__ vb,
    const float* __restrict__ nco,
    const float* __restrict__ qxt, const float* __restrict__ vxt,
    const float* __restrict__ qrt, const float* __restrict__ vrt,
    const float* __restrict__ lgt,
    ushort* __restrict__ aout)
{
    __shared__ __align__(16) float dbuf[64 * DBS];   // 11,264 B
    __shared__ __align__(16) ushort U[11264];        // 22,528 B overlay region
    __shared__ __align__(16) float cwf[64 * 6];      //  1,536 B (35.3 KB total)
    // Phase A overlays:
    ushort* q_s  = U;              // [64][40] = 2560 ushorts
    ushort* tbl  = U + 2560;       // [128][40] = 5120 ushorts, ends 7680
    // Phase B overlays:
    ushort* attn_s = U;            // [64][72] = 4608 ushorts
    ushort* v_t    = U + 4608;     // [32][72] = 2304, ends 6912
    ushort* vtbl   = U + 6912;     // [32][136] = 4352, ends 11264

    const int tid = threadIdx.x;
    const int n = blockIdx.x >> 3;
    const int h = blockIdx.x & 7;
    const int w = tid >> 6;
    const int lane = tid & 63;
    const int l4 = tid & 15;
    const int quad = (tid >> 4) & 3;

    const size_t base = (size_t)((n * 8 + h) * 64) * 32;

    {
        int row = tid >> 2, part = tid & 3;
        *(uint4*)&q_s[row * 40 + part * 8] = *(const uint4*)(qb + base + tid * 8);
    }
    if (tid < 64) {
        const float* cp = nco + (size_t)(n * 64 + tid) * 6;
        cwf[tid * 6 + 0] = cp[0] * 4.f; cwf[tid * 6 + 1] = cp[1] * 4.f;
        cwf[tid * 6 + 2] = cp[2] * 4.f; cwf[tid * 6 + 3] = cp[3] * 8.f;
        cwf[tid * 6 + 4] = cp[4] * 8.f; cwf[tid * 6 + 5] = cp[5] * 8.f;
    }

    auto stageTbl = [&](const float* tbg, int R, int Rpad) {
        for (int e = tid; e < R * 4; e += 256) {
            int r = e >> 2, part = e & 3;
            const float* src = tbg + (size_t)r * 256 + part * 8;
            float4 f0 = *(const float4*)src, f1 = *(const float4*)(src + 4);
            union { ushort u[8]; uint4 v; } pk;
            pk.u[0] = f2bf(f0.x); pk.u[1] = f2bf(f0.y); pk.u[2] = f2bf(f0.z); pk.u[3] = f2bf(f0.w);
            pk.u[4] = f2bf(f1.x); pk.u[5] = f2bf(f1.y); pk.u[6] = f2bf(f1.z); pk.u[7] = f2bf(f1.w);
            *(uint4*)&tbl[r * 40 + part * 8] = pk.v;
        }
        for (int e = tid; e < (Rpad - R) * 40; e += 256) tbl[R * 40 + e] = 0;
    };
    auto stageVtbl = [&](const float* tbg, int R) {
        for (int e = tid; e < R * 4; e += 256) {
            int r = e >> 2, part = e & 3;
            const float* src = tbg + (size_t)r * 256 + part * 8;
            float4 f0 = *(const float4*)src, f1 = *(const float4*)(src + 4);
            int d0 = part * 8;
            vtbl[(d0 + 0) * 136 + r] = f2bf(f0.x);
            vtbl[(d0 + 1) * 136 + r] = f2bf(f0.y);
            vtbl[(d0 + 2) * 136 + r] = f2bf(f0.z);
            vtbl[(d0 + 3) * 136 + r] = f2bf(f0.w);
            vtbl[(d0 + 4) * 136 + r] = f2bf(f1.x);
            vtbl[(d0 + 5) * 136 + r] = f2bf(f1.y);
            vtbl[(d0 + 6) * 136 + r] = f2bf(f1.z);
            vtbl[(d0 + 7) * 136 + r] = f2bf(f1.w);
        }
    };
    auto stageVt = [&]() {
        int j = tid >> 2, d0 = (tid & 3) * 8;
        uint4 pk = *(const uint4*)(vb + base + tid * 8);
        const ushort* u = (const ushort*)&pk;
#pragma unroll
        for (int ii = 0; ii < 8; ++ii) v_t[(d0 + ii) * 72 + j] = u[ii];
    };

    // ---- load logitsT transposed into lg[i own-row][j col] (f32x4) ----
    float lg[4][4];
    {
        const float* lp = lgt + (size_t)(n * 8 + h) * 4096;
        int i0 = w * 16 + quad * 4;
#pragma unroll
        for (int tt = 0; tt < 4; ++tt) {
            f32x4 v = *(const f32x4*)(lp + (size_t)(tt * 16 + l4) * 64 + i0);
            lg[tt][0] = v[0]; lg[tt][1] = v[1]; lg[tt][2] = v[2]; lg[tt][3] = v[3];
        }
    }

    int ibase[4];
#pragma unroll
    for (int r = 0; r < 4; ++r) ibase[r] = (w * 16 + quad * 4 + r) * DBS;

    auto tgemmC = [&](const ushort* a_s, int c, int T) {
        short8 af = *(const short8*)&a_s[(w * 16 + l4) * 40 + quad * 8];
        const int NT = (T == 40) ? 3 : 2;
        for (int tt = 0; tt < NT; ++tt) {
            short8 bf = *(const short8*)&tbl[(c * T + tt * 16 + l4) * 40 + quad * 8];
            f32x4 a = {0.f, 0.f, 0.f, 0.f};
            a = __builtin_amdgcn_mfma_f32_16x16x32_bf16(af, bf, a, 0, 0, 0);
            int col = tt * 16 + l4;
            int rb = w * 16 + quad * 4;
            if (col < T) {
                dbuf[(rb + 0) * DBS + col] = a[0];
                dbuf[(rb + 1) * DBS + col] = a[1];
                dbuf[(rb + 2) * DBS + col] = a[2];
                dbuf[(rb + 3) * DBS + col] = a[3];
            }
        }
    };
    auto zeroOwn = [&]() {
        float4 z = {0.f, 0.f, 0.f, 0.f};
        float4* rb = (float4*)&dbuf[w * 16 * DBS];     // 16*44 = 704 f = 176 f4
        for (int v = lane; v < 176; v += 64) rb[v] = z;
    };

    stageTbl(qxt + h * 32, 120, 128);
    __syncthreads();

    // ---- precompute packed bin indices: x = floor(c_own_i - c_col_j) + off ----
    unsigned idxp[24];
    {
        float co[4][6], cl[4][6];
#pragma unroll
        for (int r = 0; r < 4; ++r) {
            int i = w * 16 + quad * 4 + r;
#pragma unroll
            for (int c6 = 0; c6 < 6; ++c6) co[r][c6] = cwf[i * 6 + c6];
        }
#pragma unroll
        for (int tt = 0; tt < 4; ++tt) {
            int j = tt * 16 + l4;
#pragma unroll
            for (int c6 = 0; c6 < 6; ++c6) cl[tt][c6] = cwf[j * 6 + c6];
        }
#pragma unroll
        for (int c6 = 0; c6 < 6; ++c6) {
            const int off = (c6 < 3) ? 20 : 16, hi = (c6 < 3) ? 39 : 31;
#pragma unroll
            for (int tt = 0; tt < 4; ++tt) {
                unsigned p = 0;
#pragma unroll
                for (int r = 0; r < 4; ++r) {
                    int x = min(max((int)floorf(co[r][c6] - cl[tt][c6]) + off, 0), hi);
                    p |= (unsigned)x << (8 * r);
                }
                idxp[c6 * 4 + tt] = p;
            }
        }
    }

    auto gatherC = [&](int cc) {
#pragma unroll
        for (int tt = 0; tt < 4; ++tt) {
            unsigned p = idxp[cc * 4 + tt];
#pragma unroll
            for (int r = 0; r < 4; ++r) {
                int x = (p >> (8 * r)) & 255;
                lg[tt][r] += dbuf[ibase[r] + x];
            }
        }
    };
    // fixed-point scatter: native ds_add_u32 (no FP-CAS loop)
    auto scatterC = [&](int cc) {
        unsigned* bb = (unsigned*)dbuf;
#pragma unroll
        for (int tt = 0; tt < 4; ++tt) {
            unsigned p = idxp[cc * 4 + tt];
#pragma unroll
            for (int r = 0; r < 4; ++r) {
                int x = (p >> (8 * r)) & 255;
                unsigned q = (unsigned)(lg[tt][r] * FXS + 0.5f);
                atomicAdd(&bb[ibase[r] + x], q);
            }
        }
    };

    // ---- bias_q xyz: wave-private ----
    tgemmC(q_s, 0, 40); LFENCE();
    gatherC(0); LFENCE();
    tgemmC(q_s, 1, 40); LFENCE();
    gatherC(1); LFENCE();
    tgemmC(q_s, 2, 40);
    __syncthreads();                       // all waves done reading tbl(qxt)
    gatherC(2);
    stageTbl(qrt + h * 32, 96, 96);
    __syncthreads();
    // ---- bias_q rgb ----
    tgemmC(q_s, 0, 32); LFENCE();
    gatherC(3); LFENCE();
    tgemmC(q_s, 1, 32); LFENCE();
    gatherC(4); LFENCE();
    tgemmC(q_s, 2, 32);
    __syncthreads();                       // tbl/q_s regions go dead here
    gatherC(5);
    stageVtbl(vxt + h * 32, 120);
    stageVt();
    __syncthreads();

    // ---- softmax ----
#pragma unroll
    for (int reg = 0; reg < 4; ++reg) {
        float m = fmaxf(fmaxf(lg[0][reg], lg[1][reg]), fmaxf(lg[2][reg], lg[3][reg]));
        m = fmaxf(m, __shfl_xor(m, 1));
        m = fmaxf(m, __shfl_xor(m, 2));
        m = fmaxf(m, __shfl_xor(m, 4));
        m = fmaxf(m, __shfl_xor(m, 8));
        float s = 0.f;
#pragma unroll
        for (int tt = 0; tt < 4; ++tt) { lg[tt][reg] = __expf(lg[tt][reg] - m); s += lg[tt][reg]; }
        s += __shfl_xor(s, 1); s += __shfl_xor(s, 2);
        s += __shfl_xor(s, 4); s += __shfl_xor(s, 8);
        float inv = 1.f / s;
#pragma unroll
        for (int tt = 0; tt < 4; ++tt) lg[tt][reg] *= inv;
    }
#pragma unroll
    for (int tt = 0; tt < 4; ++tt)
#pragma unroll
        for (int reg = 0; reg < 4; ++reg)
            attn_s[(w * 16 + quad * 4 + reg) * 72 + tt * 16 + l4] = f2bf(lg[tt][reg]);
    zeroOwn();
    __syncthreads();

    // ---- AV ----
    f32x4 acc0 = {0.f, 0.f, 0.f, 0.f}, acc1 = {0.f, 0.f, 0.f, 0.f};
#pragma unroll
    for (int s = 0; s < 2; ++s) {
        short8 af = *(const short8*)&attn_s[(w * 16 + l4) * 72 + s * 32 + quad * 8];
        short8 b0 = *(const short8*)&v_t[l4 * 72 + s * 32 + quad * 8];
        short8 b1 = *(const short8*)&v_t[(16 + l4) * 72 + s * 32 + quad * 8];
        acc0 = __builtin_amdgcn_mfma_f32_16x16x32_bf16(af, b0, acc0, 0, 0, 0);
        acc1 = __builtin_amdgcn_mfma_f32_16x16x32_bf16(af, b1, acc1, 0, 0, 0);
    }

    // bins are fixed-point u32 now: read back as (float)u * 2^-24
    auto atgemmC = [&](int c, int T, int S) {
#pragma unroll
        for (int s = 0; s < S; ++s) {
            int koff = s * 32 + quad * 8;
            short8 af = {0, 0, 0, 0, 0, 0, 0, 0};
            int kr = 0;
            if (koff < T) {
                const unsigned* ap = (const unsigned*)&dbuf[(w * 16 + l4) * DBS + koff];
                uint4 u0 = *(const uint4*)ap;
                uint4 u1 = *(const uint4*)(ap + 4);
                af[0] = (short)f2bf((float)u0.x * FXI); af[1] = (short)f2bf((float)u0.y * FXI);
                af[2] = (short)f2bf((float)u0.z * FXI); af[3] = (short)f2bf((float)u0.w * FXI);
                af[4] = (short)f2bf((float)u1.x * FXI); af[5] = (short)f2bf((float)u1.y * FXI);
                af[6] = (short)f2bf((float)u1.z * FXI); af[7] = (short)f2bf((float)u1.w * FXI);
                kr = c * T + koff;
            }
            short8 b0 = *(const short8*)&vtbl[l4 * 136 + kr];
            short8 b1 = *(const short8*)&vtbl[(16 + l4) * 136 + kr];
            acc0 = __builtin_amdgcn_mfma_f32_16x16x32_bf16(af, b0, acc0, 0, 0, 0);
            acc1 = __builtin_amdgcn_mfma_f32_16x16x32_bf16(af, b1, acc1, 0, 0, 0);
        }
    };

    // ---- value-bias xyz: all dbuf traffic wave-private -> fences only ----
    scatterC(0); LFENCE();
    atgemmC(0, 40, 2); LFENCE();
    zeroOwn(); LFENCE();
    scatterC(1); LFENCE();
    atgemmC(1, 40, 2); LFENCE();
    zeroOwn(); LFENCE();
    scatterC(2); LFENCE();
    atgemmC(2, 40, 2);
    __syncthreads();                       // all waves done reading vtbl(vxt)
    zeroOwn();
    stageVtbl(vrt + h * 32, 96);
    __syncthreads();

    // ---- value-bias rgb ----
    scatterC(3); LFENCE();
    atgemmC(0, 32, 1); LFENCE();
    zeroOwn(); LFENCE();
    scatterC(4); LFENCE();
    atgemmC(1, 32, 1); LFENCE();
    zeroOwn(); LFENCE();
    scatterC(5); LFENCE();
    atgemmC(2, 32, 1);

    // ---- epilogue: bf16 ao[i][h*32+d] ----
    {
        ushort* op = aout + (size_t)(n * 64 + w * 16 + quad * 4) * 256 + h * 32;
#pragma unroll
        for (int reg = 0; reg < 4; ++reg) {
            op[reg * 256 + l4] = f2bf(acc0[reg]);
            op[reg * 256 + 16 + l4] = f2bf(acc1[reg]);
        }
    }
}

// ---------------------------------------------------------------------------
// Proj GEMM (bf16 MFMA): out = ao(bf16) @ proj_w(fp32, cast inline)^T + pb
// ---------------------------------------------------------------------------
__global__ __launch_bounds__(256) void k_proj(
    const ushort* __restrict__ A, const float* __restrict__ B,
    const float* __restrict__ bias, float* __restrict__ out)
{
    __shared__ __align__(16) ushort a_s[128 * 72];
    __shared__ __align__(16) ushort b_s[64 * 72];
    const int tid = threadIdx.x;
    const int m0 = blockIdx.y * 128;
    const int n0 = blockIdx.x * 64;
    const int w = tid >> 6, wm = w >> 1, wn = w & 1;
    const int l4 = tid & 15, quad = (tid >> 4) & 3;
    f32x4 acc[4][2];
#pragma unroll
    for (int mt = 0; mt < 4; ++mt)
#pragma unroll
        for (int nt = 0; nt < 2; ++nt) acc[mt][nt] = (f32x4){0.f, 0.f, 0.f, 0.f};

    for (int k0 = 0; k0 < 256; k0 += 64) {
#pragma unroll
        for (int l = 0; l < 4; ++l) {
            int e = tid + l * 256;
            int row = e >> 3, kq = e & 7;
            *(uint4*)&a_s[row * 72 + kq * 8] =
                *(const uint4*)(A + (size_t)(m0 + row) * 256 + k0 + kq * 8);
        }
#pragma unroll
        for (int l = 0; l < 2; ++l) {
            int e = tid + l * 256;
            int row = e >> 3, kq = e & 7;
            const float* bp = B + (size_t)(n0 + row) * 256 + k0 + kq * 8;
            float4 v0 = *(const float4*)bp, v1 = *(const float4*)(bp + 4);
            union { ushort u[8]; uint4 v; } pk;
            pk.u[0] = f2bf(v0.x); pk.u[1] = f2bf(v0.y); pk.u[2] = f2bf(v0.z); pk.u[3] = f2bf(v0.w);
            pk.u[4] = f2bf(v1.x); pk.u[5] = f2bf(v1.y); pk.u[6] = f2bf(v1.z); pk.u[7] = f2bf(v1.w);
            *(uint4*)&b_s[row * 72 + kq * 8] = pk.v;
        }
        __syncthreads();
#pragma unroll
        for (int kh = 0; kh < 2; ++kh) {
            short8 bf0 = *(const short8*)&b_s[(wn * 32 + l4) * 72 + kh * 32 + quad * 8];
            short8 bf1 = *(const short8*)&b_s[(wn * 32 + 16 + l4) * 72 + kh * 32 + quad * 8];
#pragma unroll
            for (int mt = 0; mt < 4; ++mt) {
                short8 af = *(const short8*)&a_s[(wm * 64 + mt * 16 + l4) * 72 + kh * 32 + quad * 8];
                acc[mt][0] = __builtin_amdgcn_mfma_f32_16x16x32_bf16(af, bf0, acc[mt][0], 0, 0, 0);
                acc[mt][1] = __builtin_amdgcn_mfma_f32_16x16x32_bf16(af, bf1, acc[mt][1], 0, 0, 0);
            }
        }
        __syncthreads();
    }
#pragma unroll
    for (int nt = 0; nt < 2; ++nt) {
        int c = n0 + wn * 32 + nt * 16 + l4;
        float bv = bias[c];
#pragma unroll
        for (int mt = 0; mt < 4; ++mt) {
            int mbase = m0 + wm * 64 + mt * 16 + quad * 4;
#pragma unroll
            for (int reg = 0; reg < 4; ++reg)
                out[(size_t)(mbase + reg) * 256 + c] = acc[mt][nt][reg] + bv;
        }
    }
}

extern "C" void kernel_launch(void* const* d_in, const int* in_sizes, int n_in,
                              void* d_out, int out_size, void* d_ws, size_t ws_size,
                              hipStream_t stream)
{
    const float* feats = (const float*)d_in[0];
    const float* nco   = (const float*)d_in[1];
    const float* qkvw  = (const float*)d_in[2];
    const float* qkvb  = (const float*)d_in[3];
    const float* qxt   = (const float*)d_in[4];
    const float* kxt   = (const float*)d_in[5];
    const float* vxt   = (const float*)d_in[6];
    const float* qrt   = (const float*)d_in[7];
    const float* krt   = (const float*)d_in[8];
    const float* vrt   = (const float*)d_in[9];
    const float* pw    = (const float*)d_in[10];
    const float* pb    = (const float*)d_in[11];
    float* out = (float*)d_out;

    ushort* qb  = (ushort*)d_ws;                       // [128][8][64][32] bf16, 4 MB
    ushort* kb  = qb + (size_t)2097152;
    ushort* vb  = kb + (size_t)2097152;
    ushort* aob = vb + (size_t)2097152;                // [8192][256] bf16, 4 MB
    float*  lgt = (float*)(aob + (size_t)2097152);     // [1024][64][64] f32, 16.7 MB

    k_qkv<<<dim3(12, 64), 256, 0, stream>>>(feats, qkvw, qkvb, qb, kb, vb);
    k_bias<<<dim3(1024), 256, 0, stream>>>(qb, kb, nco, kxt, krt, lgt);
    k_av<<<dim3(1024), 256, 0, stream>>>(qb, vb, nco, qxt, vxt, qrt, vrt, lgt, aob);
    k_proj<<<dim3(4, 64), 256, 0, stream>>>(aob, pw, pb, out);
}

// Round 8
// 149.122 us; speedup vs baseline: 2.1252x; 1.0305x over previous
//
#include <hip/hip_runtime.h>

// DIM=256 H=8 HD=32 W=64 N=8192 nw=128
// xyz: T=40, off=20, hi=39 ; rgb: T=32, off=16, hi=31
// table element ((c*T+t)*8+h)*32+d == r*256 + h*32 + d, r=c*T+t

typedef __attribute__((ext_vector_type(8))) short short8;
typedef __attribute__((ext_vector_type(4))) float f32x4;

__device__ __forceinline__ unsigned short f2bf(float f) {
    union { float f; unsigned int u; } v; v.f = f;
    unsigned int r = v.u + 0x7FFFu + ((v.u >> 16) & 1u);
    return (unsigned short)(r >> 16);
}

// Wave-local ordering fence: drains this wave's outstanding DS ops.
#define LFENCE() asm volatile("s_waitcnt lgkmcnt(0)" ::: "memory")

// ---------------------------------------------------------------------------
// Round-16: lean GEMMs. r7 confirmed atomics fix (272->153.7); remaining
// budget ~= fill 43 (harness) + k_bias 15 + k_av ~38 + GEMMs+gaps ~55.
// k_qkv was re-reading feats as FP32 12x with 48 f2bf/thread/iter; k_proj
// ran at 1 block/CU converting proj_w inline in all 256 blocks.
// Fix: k_cast precasts feats/qkv_w/proj_w to bf16 once (~3us); both GEMMs
// retiled to 64x64 (qkv 1536 blocks = 6/CU, proj 512 = 2/CU) with pure
// uint4 bf16 staging (zero VALU conversion in hot loop, acc 2x2 = 16 AGPR).
// Attention kernels (k_bias/k_av) untouched from r7.
// ---------------------------------------------------------------------------
__global__ __launch_bounds__(256) void k_cast(
    const float* __restrict__ feats, const float* __restrict__ qkvw,
    const float* __restrict__ pw,
    ushort* __restrict__ fb, ushort* __restrict__ qwb, ushort* __restrict__ pwb)
{
    int t = blockIdx.x * 256 + threadIdx.x;   // each thread casts 8 floats
    const float* src; ushort* dst; int off;
    if (t < 262144)            { src = feats; dst = fb;  off = t; }
    else if (t < 286720)       { src = qkvw;  dst = qwb; off = t - 262144; }
    else                       { src = pw;    dst = pwb; off = t - 286720; }
    const float* s = src + (size_t)off * 8;
    float4 v0 = *(const float4*)s, v1 = *(const float4*)(s + 4);
    union { ushort u[8]; uint4 v; } pk;
    pk.u[0] = f2bf(v0.x); pk.u[1] = f2bf(v0.y); pk.u[2] = f2bf(v0.z); pk.u[3] = f2bf(v0.w);
    pk.u[4] = f2bf(v1.x); pk.u[5] = f2bf(v1.y); pk.u[6] = f2bf(v1.z); pk.u[7] = f2bf(v1.w);
    *(uint4*)(dst + (size_t)off * 8) = pk.v;
}

// ---------------------------------------------------------------------------
// QKV GEMM, 64x64 tiles, pure-bf16 staging.
// ---------------------------------------------------------------------------
__global__ __launch_bounds__(256) void k_qkv(
    const ushort* __restrict__ A, const ushort* __restrict__ B,
    const float* __restrict__ bias,
    ushort* __restrict__ qb, ushort* __restrict__ kb, ushort* __restrict__ vb)
{
    __shared__ __align__(16) ushort a_s[64 * 72];
    __shared__ __align__(16) ushort b_s[64 * 72];
    const int tid = threadIdx.x;
    const int m0 = blockIdx.y * 64;
    const int n0 = blockIdx.x * 64;
    const int w = tid >> 6, wm = w >> 1, wn = w & 1;
    const int l4 = tid & 15, quad = (tid >> 4) & 3;
    f32x4 acc[2][2];
#pragma unroll
    for (int mt = 0; mt < 2; ++mt)
#pragma unroll
        for (int nt = 0; nt < 2; ++nt) acc[mt][nt] = (f32x4){0.f, 0.f, 0.f, 0.f};

    for (int k0 = 0; k0 < 256; k0 += 64) {
#pragma unroll
        for (int l = 0; l < 2; ++l) {
            int e = tid + l * 256;
            int row = e >> 3, kq = e & 7;
            *(uint4*)&a_s[row * 72 + kq * 8] =
                *(const uint4*)(A + (size_t)(m0 + row) * 256 + k0 + kq * 8);
            *(uint4*)&b_s[row * 72 + kq * 8] =
                *(const uint4*)(B + (size_t)(n0 + row) * 256 + k0 + kq * 8);
        }
        __syncthreads();
#pragma unroll
        for (int kh = 0; kh < 2; ++kh) {
            short8 bf0 = *(const short8*)&b_s[(wn * 32 + l4) * 72 + kh * 32 + quad * 8];
            short8 bf1 = *(const short8*)&b_s[(wn * 32 + 16 + l4) * 72 + kh * 32 + quad * 8];
#pragma unroll
            for (int mt = 0; mt < 2; ++mt) {
                short8 af = *(const short8*)&a_s[(wm * 32 + mt * 16 + l4) * 72 + kh * 32 + quad * 8];
                acc[mt][0] = __builtin_amdgcn_mfma_f32_16x16x32_bf16(af, bf0, acc[mt][0], 0, 0, 0);
                acc[mt][1] = __builtin_amdgcn_mfma_f32_16x16x32_bf16(af, bf1, acc[mt][1], 0, 0, 0);
            }
        }
        __syncthreads();
    }
#pragma unroll
    for (int nt = 0; nt < 2; ++nt) {
        int c = n0 + wn * 32 + nt * 16 + l4;
        float bv = bias[c];
        int s = c >> 8, rem = c & 255, h = rem >> 5, d = rem & 31;
        ushort* dst = (s == 0) ? qb : ((s == 1) ? kb : vb);
        float mul = (s == 0) ? 0.17677669529663687f : 1.0f;
#pragma unroll
        for (int mt = 0; mt < 2; ++mt) {
            int mbase = m0 + wm * 32 + mt * 16 + quad * 4;
#pragma unroll
            for (int reg = 0; reg < 4; ++reg) {
                int m = mbase + reg;
                int nw = m >> 6, ii = m & 63;
                dst[((size_t)((nw * 8 + h) * 64 + ii)) * 32 + d] = f2bf((acc[mt][nt][reg] + bv) * mul);
            }
        }
    }
}

// ---------------------------------------------------------------------------
// Attention (r7, unchanged): k_bias + k_av with fixed-point native atomics.
// ---------------------------------------------------------------------------
#define DBS 44
#define FXS 16777216.0f
#define FXI (1.0f / 16777216.0f)

__global__ __launch_bounds__(256, 2) void k_bias(
    const ushort* __restrict__ qb, const ushort* __restrict__ kb,
    const float* __restrict__ nco,
    const float* __restrict__ kxt, const float* __restrict__ krt,
    float* __restrict__ lgt)
{
    __shared__ __align__(16) float dbuf[64 * DBS];
    __shared__ __align__(16) ushort q_s[64 * 40];
    __shared__ __align__(16) ushort k_s[64 * 40];
    __shared__ __align__(16) ushort tbl[128 * 40];
    __shared__ __align__(16) float cwf[64 * 6];

    const int tid = threadIdx.x;
    const int n = blockIdx.x >> 3;
    const int h = blockIdx.x & 7;
    const int w = tid >> 6;
    const int l4 = tid & 15;
    const int quad = (tid >> 4) & 3;

    const size_t base = (size_t)((n * 8 + h) * 64) * 32;

    {
        int row = tid >> 2, part = tid & 3;
        *(uint4*)&q_s[row * 40 + part * 8] = *(const uint4*)(qb + base + tid * 8);
        *(uint4*)&k_s[row * 40 + part * 8] = *(const uint4*)(kb + base + tid * 8);
    }
    if (tid < 64) {
        const float* cp = nco + (size_t)(n * 64 + tid) * 6;
        cwf[tid * 6 + 0] = cp[0] * 4.f; cwf[tid * 6 + 1] = cp[1] * 4.f;
        cwf[tid * 6 + 2] = cp[2] * 4.f; cwf[tid * 6 + 3] = cp[3] * 8.f;
        cwf[tid * 6 + 4] = cp[4] * 8.f; cwf[tid * 6 + 5] = cp[5] * 8.f;
    }

    auto stageTbl = [&](const float* tbg, int R, int Rpad) {
        for (int e = tid; e < R * 4; e += 256) {
            int r = e >> 2, part = e & 3;
            const float* src = tbg + (size_t)r * 256 + part * 8;
            float4 f0 = *(const float4*)src, f1 = *(const float4*)(src + 4);
            union { ushort u[8]; uint4 v; } pk;
            pk.u[0] = f2bf(f0.x); pk.u[1] = f2bf(f0.y); pk.u[2] = f2bf(f0.z); pk.u[3] = f2bf(f0.w);
            pk.u[4] = f2bf(f1.x); pk.u[5] = f2bf(f1.y); pk.u[6] = f2bf(f1.z); pk.u[7] = f2bf(f1.w);
            *(uint4*)&tbl[r * 40 + part * 8] = pk.v;
        }
        for (int e = tid; e < (Rpad - R) * 40; e += 256) tbl[R * 40 + e] = 0;
    };

    float lg[4][4];   // TRANSPOSED: row j = w*16+quad*4+reg, col i = tt*16+l4
    int ibase[4];
#pragma unroll
    for (int r = 0; r < 4; ++r) ibase[r] = (w * 16 + quad * 4 + r) * DBS;

    auto tgemmC = [&](const ushort* a_s, int c, int T) {
        short8 af = *(const short8*)&a_s[(w * 16 + l4) * 40 + quad * 8];
        const int NT = (T == 40) ? 3 : 2;
        for (int tt = 0; tt < NT; ++tt) {
            short8 bf = *(const short8*)&tbl[(c * T + tt * 16 + l4) * 40 + quad * 8];
            f32x4 a = {0.f, 0.f, 0.f, 0.f};
            a = __builtin_amdgcn_mfma_f32_16x16x32_bf16(af, bf, a, 0, 0, 0);
            int col = tt * 16 + l4;
            int rb = w * 16 + quad * 4;
            if (col < T) {
                dbuf[(rb + 0) * DBS + col] = a[0];
                dbuf[(rb + 1) * DBS + col] = a[1];
                dbuf[(rb + 2) * DBS + col] = a[2];
                dbuf[(rb + 3) * DBS + col] = a[3];
            }
        }
    };

    stageTbl(kxt + h * 32, 120, 128);
    __syncthreads();

    unsigned idxp[24];
    {
        float co[4][6], cl[4][6];
#pragma unroll
        for (int r = 0; r < 4; ++r) {
            int j = w * 16 + quad * 4 + r;
#pragma unroll
            for (int c6 = 0; c6 < 6; ++c6) co[r][c6] = cwf[j * 6 + c6];
        }
#pragma unroll
        for (int tt = 0; tt < 4; ++tt) {
            int i = tt * 16 + l4;
#pragma unroll
            for (int c6 = 0; c6 < 6; ++c6) cl[tt][c6] = cwf[i * 6 + c6];
        }
#pragma unroll
        for (int c6 = 0; c6 < 6; ++c6) {
            const int off = (c6 < 3) ? 20 : 16, hi = (c6 < 3) ? 39 : 31;
#pragma unroll
            for (int tt = 0; tt < 4; ++tt) {
                unsigned p = 0;
#pragma unroll
                for (int r = 0; r < 4; ++r) {
                    int x = min(max((int)floorf(cl[tt][c6] - co[r][c6]) + off, 0), hi);
                    p |= (unsigned)x << (8 * r);
                }
                idxp[c6 * 4 + tt] = p;
            }
        }
    }

    auto gatherT = [&](int cc) {
#pragma unroll
        for (int tt = 0; tt < 4; ++tt) {
            unsigned p = idxp[cc * 4 + tt];
#pragma unroll
            for (int r = 0; r < 4; ++r) {
                int x = (p >> (8 * r)) & 255;
                lg[tt][r] += dbuf[ibase[r] + x];
            }
        }
    };

    {
        short8 ak = *(const short8*)&k_s[(w * 16 + l4) * 40 + quad * 8];
#pragma unroll
        for (int tt = 0; tt < 4; ++tt) {
            short8 bq = *(const short8*)&q_s[(tt * 16 + l4) * 40 + quad * 8];
            f32x4 r = {0.f, 0.f, 0.f, 0.f};
            r = __builtin_amdgcn_mfma_f32_16x16x32_bf16(ak, bq, r, 0, 0, 0);
            lg[tt][0] = r[0]; lg[tt][1] = r[1]; lg[tt][2] = r[2]; lg[tt][3] = r[3];
        }
    }

    tgemmC(k_s, 0, 40); LFENCE();
    gatherT(0); LFENCE();
    tgemmC(k_s, 1, 40); LFENCE();
    gatherT(1); LFENCE();
    tgemmC(k_s, 2, 40); LFENCE();
    gatherT(2);
    __syncthreads();
    stageTbl(krt + h * 32, 96, 96);
    __syncthreads();
    tgemmC(k_s, 0, 32); LFENCE();
    gatherT(3); LFENCE();
    tgemmC(k_s, 1, 32); LFENCE();
    gatherT(4); LFENCE();
    tgemmC(k_s, 2, 32); LFENCE();
    gatherT(5);

    {
        float* lp = lgt + (size_t)(n * 8 + h) * 4096;
#pragma unroll
        for (int tt = 0; tt < 4; ++tt)
#pragma unroll
            for (int reg = 0; reg < 4; ++reg)
                lp[(w * 16 + quad * 4 + reg) * 64 + tt * 16 + l4] = lg[tt][reg];
    }
}

__global__ __launch_bounds__(256, 2) void k_av(
    const ushort* __restrict__ qb, const ushort* __restrict__ vb,
    const float* __restrict__ nco,
    const float* __restrict__ qxt, const float* __restrict__ vxt,
    const float* __restrict__ qrt, const float* __restrict__ vrt,
    const float* __restrict__ lgt,
    ushort* __restrict__ aout)
{
    __shared__ __align__(16) float dbuf[64 * DBS];
    __shared__ __align__(16) ushort U[11264];
    __shared__ __align__(16) float cwf[64 * 6];
    ushort* q_s  = U;              // [64][40]
    ushort* tbl  = U + 2560;       // [128][40]
    ushort* attn_s = U;            // [64][72]
    ushort* v_t    = U + 4608;     // [32][72]
    ushort* vtbl   = U + 6912;     // [32][136]

    const int tid = threadIdx.x;
    const int n = blockIdx.x >> 3;
    const int h = blockIdx.x & 7;
    const int w = tid >> 6;
    const int lane = tid & 63;
    const int l4 = tid & 15;
    const int quad = (tid >> 4) & 3;

    const size_t base = (size_t)((n * 8 + h) * 64) * 32;

    {
        int row = tid >> 2, part = tid & 3;
        *(uint4*)&q_s[row * 40 + part * 8] = *(const uint4*)(qb + base + tid * 8);
    }
    if (tid < 64) {
        const float* cp = nco + (size_t)(n * 64 + tid) * 6;
        cwf[tid * 6 + 0] = cp[0] * 4.f; cwf[tid * 6 + 1] = cp[1] * 4.f;
        cwf[tid * 6 + 2] = cp[2] * 4.f; cwf[tid * 6 + 3] = cp[3] * 8.f;
        cwf[tid * 6 + 4] = cp[4] * 8.f; cwf[tid * 6 + 5] = cp[5] * 8.f;
    }

    auto stageTbl = [&](const float* tbg, int R, int Rpad) {
        for (int e = tid; e < R * 4; e += 256) {
            int r = e >> 2, part = e & 3;
            const float* src = tbg + (size_t)r * 256 + part * 8;
            float4 f0 = *(const float4*)src, f1 = *(const float4*)(src + 4);
            union { ushort u[8]; uint4 v; } pk;
            pk.u[0] = f2bf(f0.x); pk.u[1] = f2bf(f0.y); pk.u[2] = f2bf(f0.z); pk.u[3] = f2bf(f0.w);
            pk.u[4] = f2bf(f1.x); pk.u[5] = f2bf(f1.y); pk.u[6] = f2bf(f1.z); pk.u[7] = f2bf(f1.w);
            *(uint4*)&tbl[r * 40 + part * 8] = pk.v;
        }
        for (int e = tid; e < (Rpad - R) * 40; e += 256) tbl[R * 40 + e] = 0;
    };
    auto stageVtbl = [&](const float* tbg, int R) {
        for (int e = tid; e < R * 4; e += 256) {
            int r = e >> 2, part = e & 3;
            const float* src = tbg + (size_t)r * 256 + part * 8;
            float4 f0 = *(const float4*)src, f1 = *(const float4*)(src + 4);
            int d0 = part * 8;
            vtbl[(d0 + 0) * 136 + r] = f2bf(f0.x);
            vtbl[(d0 + 1) * 136 + r] = f2bf(f0.y);
            vtbl[(d0 + 2) * 136 + r] = f2bf(f0.z);
            vtbl[(d0 + 3) * 136 + r] = f2bf(f0.w);
            vtbl[(d0 + 4) * 136 + r] = f2bf(f1.x);
            vtbl[(d0 + 5) * 136 + r] = f2bf(f1.y);
            vtbl[(d0 + 6) * 136 + r] = f2bf(f1.z);
            vtbl[(d0 + 7) * 136 + r] = f2bf(f1.w);
        }
    };
    auto stageVt = [&]() {
        int j = tid >> 2, d0 = (tid & 3) * 8;
        uint4 pk = *(const uint4*)(vb + base + tid * 8);
        const ushort* u = (const ushort*)&pk;
#pragma unroll
        for (int ii = 0; ii < 8; ++ii) v_t[(d0 + ii) * 72 + j] = u[ii];
    };

    float lg[4][4];
    {
        const float* lp = lgt + (size_t)(n * 8 + h) * 4096;
        int i0 = w * 16 + quad * 4;
#pragma unroll
        for (int tt = 0; tt < 4; ++tt) {
            f32x4 v = *(const f32x4*)(lp + (size_t)(tt * 16 + l4) * 64 + i0);
            lg[tt][0] = v[0]; lg[tt][1] = v[1]; lg[tt][2] = v[2]; lg[tt][3] = v[3];
        }
    }

    int ibase[4];
#pragma unroll
    for (int r = 0; r < 4; ++r) ibase[r] = (w * 16 + quad * 4 + r) * DBS;

    auto tgemmC = [&](const ushort* a_s, int c, int T) {
        short8 af = *(const short8*)&a_s[(w * 16 + l4) * 40 + quad * 8];
        const int NT = (T == 40) ? 3 : 2;
        for (int tt = 0; tt < NT; ++tt) {
            short8 bf = *(const short8*)&tbl[(c * T + tt * 16 + l4) * 40 + quad * 8];
            f32x4 a = {0.f, 0.f, 0.f, 0.f};
            a = __builtin_amdgcn_mfma_f32_16x16x32_bf16(af, bf, a, 0, 0, 0);
            int col = tt * 16 + l4;
            int rb = w * 16 + quad * 4;
            if (col < T) {
                dbuf[(rb + 0) * DBS + col] = a[0];
                dbuf[(rb + 1) * DBS + col] = a[1];
                dbuf[(rb + 2) * DBS + col] = a[2];
                dbuf[(rb + 3) * DBS + col] = a[3];
            }
        }
    };
    auto zeroOwn = [&]() {
        float4 z = {0.f, 0.f, 0.f, 0.f};
        float4* rb = (float4*)&dbuf[w * 16 * DBS];
        for (int v = lane; v < 176; v += 64) rb[v] = z;
    };

    stageTbl(qxt + h * 32, 120, 128);
    __syncthreads();

    unsigned idxp[24];
    {
        float co[4][6], cl[4][6];
#pragma unroll
        for (int r = 0; r < 4; ++r) {
            int i = w * 16 + quad * 4 + r;
#pragma unroll
            for (int c6 = 0; c6 < 6; ++c6) co[r][c6] = cwf[i * 6 + c6];
        }
#pragma unroll
        for (int tt = 0; tt < 4; ++tt) {
            int j = tt * 16 + l4;
#pragma unroll
            for (int c6 = 0; c6 < 6; ++c6) cl[tt][c6] = cwf[j * 6 + c6];
        }
#pragma unroll
        for (int c6 = 0; c6 < 6; ++c6) {
            const int off = (c6 < 3) ? 20 : 16, hi = (c6 < 3) ? 39 : 31;
#pragma unroll
            for (int tt = 0; tt < 4; ++tt) {
                unsigned p = 0;
#pragma unroll
                for (int r = 0; r < 4; ++r) {
                    int x = min(max((int)floorf(co[r][c6] - cl[tt][c6]) + off, 0), hi);
                    p |= (unsigned)x << (8 * r);
                }
                idxp[c6 * 4 + tt] = p;
            }
        }
    }

    auto gatherC = [&](int cc) {
#pragma unroll
        for (int tt = 0; tt < 4; ++tt) {
            unsigned p = idxp[cc * 4 + tt];
#pragma unroll
            for (int r = 0; r < 4; ++r) {
                int x = (p >> (8 * r)) & 255;
                lg[tt][r] += dbuf[ibase[r] + x];
            }
        }
    };
    // fixed-point scatter: native ds_add_u32 (no FP-CAS loop)
    auto scatterC = [&](int cc) {
        unsigned* bb = (unsigned*)dbuf;
#pragma unroll
        for (int tt = 0; tt < 4; ++tt) {
            unsigned p = idxp[cc * 4 + tt];
#pragma unroll
            for (int r = 0; r < 4; ++r) {
                int x = (p >> (8 * r)) & 255;
                unsigned q = (unsigned)(lg[tt][r] * FXS + 0.5f);
                atomicAdd(&bb[ibase[r] + x], q);
            }
        }
    };

    tgemmC(q_s, 0, 40); LFENCE();
    gatherC(0); LFENCE();
    tgemmC(q_s, 1, 40); LFENCE();
    gatherC(1); LFENCE();
    tgemmC(q_s, 2, 40);
    __syncthreads();
    gatherC(2);
    stageTbl(qrt + h * 32, 96, 96);
    __syncthreads();
    tgemmC(q_s, 0, 32); LFENCE();
    gatherC(3); LFENCE();
    tgemmC(q_s, 1, 32); LFENCE();
    gatherC(4); LFENCE();
    tgemmC(q_s, 2, 32);
    __syncthreads();
    gatherC(5);
    stageVtbl(vxt + h * 32, 120);
    stageVt();
    __syncthreads();

    // ---- softmax ----
#pragma unroll
    for (int reg = 0; reg < 4; ++reg) {
        float m = fmaxf(fmaxf(lg[0][reg], lg[1][reg]), fmaxf(lg[2][reg], lg[3][reg]));
        m = fmaxf(m, __shfl_xor(m, 1));
        m = fmaxf(m, __shfl_xor(m, 2));
        m = fmaxf(m, __shfl_xor(m, 4));
        m = fmaxf(m, __shfl_xor(m, 8));
        float s = 0.f;
#pragma unroll
        for (int tt = 0; tt < 4; ++tt) { lg[tt][reg] = __expf(lg[tt][reg] - m); s += lg[tt][reg]; }
        s += __shfl_xor(s, 1); s += __shfl_xor(s, 2);
        s += __shfl_xor(s, 4); s += __shfl_xor(s, 8);
        float inv = 1.f / s;
#pragma unroll
        for (int tt = 0; tt < 4; ++tt) lg[tt][reg] *= inv;
    }
#pragma unroll
    for (int tt = 0; tt < 4; ++tt)
#pragma unroll
        for (int reg = 0; reg < 4; ++reg)
            attn_s[(w * 16 + quad * 4 + reg) * 72 + tt * 16 + l4] = f2bf(lg[tt][reg]);
    zeroOwn();
    __syncthreads();

    // ---- AV ----
    f32x4 acc0 = {0.f, 0.f, 0.f, 0.f}, acc1 = {0.f, 0.f, 0.f, 0.f};
#pragma unroll
    for (int s = 0; s < 2; ++s) {
        short8 af = *(const short8*)&attn_s[(w * 16 + l4) * 72 + s * 32 + quad * 8];
        short8 b0 = *(const short8*)&v_t[l4 * 72 + s * 32 + quad * 8];
        short8 b1 = *(const short8*)&v_t[(16 + l4) * 72 + s * 32 + quad * 8];
        acc0 = __builtin_amdgcn_mfma_f32_16x16x32_bf16(af, b0, acc0, 0, 0, 0);
        acc1 = __builtin_amdgcn_mfma_f32_16x16x32_bf16(af, b1, acc1, 0, 0, 0);
    }

    // bins are fixed-point u32: read back as (float)u * 2^-24
    auto atgemmC = [&](int c, int T, int S) {
#pragma unroll
        for (int s = 0; s < S; ++s) {
            int koff = s * 32 + quad * 8;
            short8 af = {0, 0, 0, 0, 0, 0, 0, 0};
            int kr = 0;
            if (koff < T) {
                const unsigned* ap = (const unsigned*)&dbuf[(w * 16 + l4) * DBS + koff];
                uint4 u0 = *(const uint4*)ap;
                uint4 u1 = *(const uint4*)(ap + 4);
                af[0] = (short)f2bf((float)u0.x * FXI); af[1] = (short)f2bf((float)u0.y * FXI);
                af[2] = (short)f2bf((float)u0.z * FXI); af[3] = (short)f2bf((float)u0.w * FXI);
                af[4] = (short)f2bf((float)u1.x * FXI); af[5] = (short)f2bf((float)u1.y * FXI);
                af[6] = (short)f2bf((float)u1.z * FXI); af[7] = (short)f2bf((float)u1.w * FXI);
                kr = c * T + koff;
            }
            short8 b0 = *(const short8*)&vtbl[l4 * 136 + kr];
            short8 b1 = *(const short8*)&vtbl[(16 + l4) * 136 + kr];
            acc0 = __builtin_amdgcn_mfma_f32_16x16x32_bf16(af, b0, acc0, 0, 0, 0);
            acc1 = __builtin_amdgcn_mfma_f32_16x16x32_bf16(af, b1, acc1, 0, 0, 0);
        }
    };

    scatterC(0); LFENCE();
    atgemmC(0, 40, 2); LFENCE();
    zeroOwn(); LFENCE();
    scatterC(1); LFENCE();
    atgemmC(1, 40, 2); LFENCE();
    zeroOwn(); LFENCE();
    scatterC(2); LFENCE();
    atgemmC(2, 40, 2);
    __syncthreads();
    zeroOwn();
    stageVtbl(vrt + h * 32, 96);
    __syncthreads();

    scatterC(3); LFENCE();
    atgemmC(0, 32, 1); LFENCE();
    zeroOwn(); LFENCE();
    scatterC(4); LFENCE();
    atgemmC(1, 32, 1); LFENCE();
    zeroOwn(); LFENCE();
    scatterC(5); LFENCE();
    atgemmC(2, 32, 1);

    {
        ushort* op = aout + (size_t)(n * 64 + w * 16 + quad * 4) * 256 + h * 32;
#pragma unroll
        for (int reg = 0; reg < 4; ++reg) {
            op[reg * 256 + l4] = f2bf(acc0[reg]);
            op[reg * 256 + 16 + l4] = f2bf(acc1[reg]);
        }
    }
}

// ---------------------------------------------------------------------------
// Proj GEMM, 64x64 tiles, pure-bf16 staging (pwb precast).
// ---------------------------------------------------------------------------
__global__ __launch_bounds__(256) void k_proj(
    const ushort* __restrict__ A, const ushort* __restrict__ B,
    const float* __restrict__ bias, float* __restrict__ out)
{
    __shared__ __align__(16) ushort a_s[64 * 72];
    __shared__ __align__(16) ushort b_s[64 * 72];
    const int tid = threadIdx.x;
    const int m0 = blockIdx.y * 64;
    const int n0 = blockIdx.x * 64;
    const int w = tid >> 6, wm = w >> 1, wn = w & 1;
    const int l4 = tid & 15, quad = (tid >> 4) & 3;
    f32x4 acc[2][2];
#pragma unroll
    for (int mt = 0; mt < 2; ++mt)
#pragma unroll
        for (int nt = 0; nt < 2; ++nt) acc[mt][nt] = (f32x4){0.f, 0.f, 0.f, 0.f};

    for (int k0 = 0; k0 < 256; k0 += 64) {
#pragma unroll
        for (int l = 0; l < 2; ++l) {
            int e = tid + l * 256;
            int row = e >> 3, kq = e & 7;
            *(uint4*)&a_s[row * 72 + kq * 8] =
                *(const uint4*)(A + (size_t)(m0 + row) * 256 + k0 + kq * 8);
            *(uint4*)&b_s[row * 72 + kq * 8] =
                *(const uint4*)(B + (size_t)(n0 + row) * 256 + k0 + kq * 8);
        }
        __syncthreads();
#pragma unroll
        for (int kh = 0; kh < 2; ++kh) {
            short8 bf0 = *(const short8*)&b_s[(wn * 32 + l4) * 72 + kh * 32 + quad * 8];
            short8 bf1 = *(const short8*)&b_s[(wn * 32 + 16 + l4) * 72 + kh * 32 + quad * 8];
#pragma unroll
            for (int mt = 0; mt < 2; ++mt) {
                short8 af = *(const short8*)&a_s[(wm * 32 + mt * 16 + l4) * 72 + kh * 32 + quad * 8];
                acc[mt][0] = __builtin_amdgcn_mfma_f32_16x16x32_bf16(af, bf0, acc[mt][0], 0, 0, 0);
                acc[mt][1] = __builtin_amdgcn_mfma_f32_16x16x32_bf16(af, bf1, acc[mt][1], 0, 0, 0);
            }
        }
        __syncthreads();
    }
#pragma unroll
    for (int nt = 0; nt < 2; ++nt) {
        int c = n0 + wn * 32 + nt * 16 + l4;
        float bv = bias[c];
#pragma unroll
        for (int mt = 0; mt < 2; ++mt) {
            int mbase = m0 + wm * 32 + mt * 16 + quad * 4;
#pragma unroll
            for (int reg = 0; reg < 4; ++reg)
                out[(size_t)(mbase + reg) * 256 + c] = acc[mt][nt][reg] + bv;
        }
    }
}

extern "C" void kernel_launch(void* const* d_in, const int* in_sizes, int n_in,
                              void* d_out, int out_size, void* d_ws, size_t ws_size,
                              hipStream_t stream)
{
    const float* feats = (const float*)d_in[0];
    const float* nco   = (const float*)d_in[1];
    const float* qkvw  = (const float*)d_in[2];
    const float* qkvb  = (const float*)d_in[3];
    const float* qxt   = (const float*)d_in[4];
    const float* kxt   = (const float*)d_in[5];
    const float* vxt   = (const float*)d_in[6];
    const float* qrt   = (const float*)d_in[7];
    const float* krt   = (const float*)d_in[8];
    const float* vrt   = (const float*)d_in[9];
    const float* pw    = (const float*)d_in[10];
    const float* pb    = (const float*)d_in[11];
    float* out = (float*)d_out;

    ushort* qb  = (ushort*)d_ws;                       // [128][8][64][32] bf16, 4 MB
    ushort* kb  = qb + (size_t)2097152;
    ushort* vb  = kb + (size_t)2097152;
    ushort* aob = vb + (size_t)2097152;                // [8192][256] bf16, 4 MB
    float*  lgt = (float*)(aob + (size_t)2097152);     // [1024][64][64] f32, 16.7 MB
    ushort* fb  = (ushort*)(lgt + (size_t)4194304);    // feats bf16, 4 MB
    ushort* qwb = fb + (size_t)2097152;                // qkv_w bf16, 384 KB
    ushort* pwb = qwb + (size_t)196608;                // proj_w bf16, 128 KB

    k_cast<<<dim3(1152), 256, 0, stream>>>(feats, qkvw, pw, fb, qwb, pwb);
    k_qkv<<<dim3(12, 128), 256, 0, stream>>>(fb, qwb, qkvb, qb, kb, vb);
    k_bias<<<dim3(1024), 256, 0, stream>>>(qb, kb, nco, kxt, krt, lgt);
    k_av<<<dim3(1024), 256, 0, stream>>>(qb, vb, nco, qxt, vxt, qrt, vrt, lgt, aob);
    k_proj<<<dim3(4, 128), 256, 0, stream>>>(aob, pwb, pb, out);
}